// Round 5
// baseline (1459.952 us; speedup 1.0000x reference)
//
#include <hip/hip_runtime.h>
#include <hip/hip_bf16.h>

// ---------- types ----------
typedef __bf16 bf16x8 __attribute__((ext_vector_type(8)));
typedef float  f32x4  __attribute__((ext_vector_type(4)));
typedef unsigned int u32x4 __attribute__((ext_vector_type(4)));
typedef unsigned short u16x8 __attribute__((ext_vector_type(8)));

__device__ inline unsigned short f2bf(float f) {
    union { __hip_bfloat16 h; unsigned short u; } cv;
    cv.h = __float2bfloat16(f);
    return cv.u;
}

// load 8 bf16 = two 8B halves at col +0 and col +16 (k-halves of 16x16x32)
__device__ inline bf16x8 load8(const unsigned short* p) {
    uint2 lo = *(const uint2*)(p);
    uint2 hi = *(const uint2*)(p + 16);
    u32x4 v; v[0] = lo.x; v[1] = lo.y; v[2] = hi.x; v[3] = hi.y;
    return __builtin_bit_cast(bf16x8, v);
}

__device__ inline f32x4 mfma16(bf16x8 a, bf16x8 b, f32x4 c) {
    return __builtin_amdgcn_mfma_f32_16x16x32_bf16(a, b, c, 0, 0, 0);
}

// window-row (global, 0..148959) -> spatial token (0..131071); false if pad
__device__ inline bool winmapT(int gg, int& T) {
    int win = gg / 98, n = gg % 98;
    int wdi = win / 190, rem = win % 190, whi = rem / 19, wwi = rem % 19;
    int td = n / 49, th = (n / 7) % 7, tw = n % 7;
    int sd = (wdi * 2 + td + 1) & 15;
    int sh = whi * 7 + th + 3; if (sh >= 70) sh -= 70;
    int sw = wwi * 7 + tw + 3; if (sw >= 133) sw -= 133;
    if (sh < 64 && sw < 128) { T = (sd * 64 + sh) * 128 + sw; return true; }
    return false;
}

// ---------- K0: mod = silu(t) @ wa1 @ wa2 + ba2  (1152 floats) ----------
__global__ __launch_bounds__(256) void mod_k(const float* __restrict__ t,
    const float* __restrict__ wa1, const float* __restrict__ wa2,
    const float* __restrict__ ba2, float* __restrict__ mod)
{
    __shared__ float st[192];
    __shared__ float a[24];
    int tid = threadIdx.x;
    if (tid < 192) { float x = t[tid]; st[tid] = x / (1.f + __expf(-x)); }
    __syncthreads();
    if (tid < 24) {
        float s = 0.f;
        for (int c = 0; c < 192; ++c) s += st[c] * wa1[c * 24 + tid];
        a[tid] = s;
    }
    __syncthreads();
    for (int j = tid; j < 1152; j += 256) {
        float s = ba2[j];
        for (int r = 0; r < 24; ++r) s += a[r] * wa2[r * 1152 + j];
        mod[j] = s;
    }
}

// ---------- K1: weight transposes (fp32 -> bf16, [N][K]) + bias table ----------
__global__ __launch_bounds__(256) void prep_k(
    const float* __restrict__ wqkv, const float* __restrict__ wproj,
    const float* __restrict__ w1, const float* __restrict__ w2,
    const float* __restrict__ relb,
    unsigned short* __restrict__ wqkvT, unsigned short* __restrict__ wprojT,
    unsigned short* __restrict__ w1T, unsigned short* __restrict__ w2T,
    float* __restrict__ bias6)
{
    int i = blockIdx.x * 256 + threadIdx.x;
    if (i < 110592) { int n = i / 192, k = i % 192; wqkvT[i] = f2bf(wqkv[k * 576 + n]); return; }
    i -= 110592;
    if (i < 36864)  { int n = i / 192, k = i % 192; wprojT[i] = f2bf(wproj[k * 192 + n]); return; }
    i -= 36864;
    if (i < 147456) { int n = i / 192, k = i % 192; w1T[i] = f2bf(w1[k * 768 + n]); return; }
    i -= 147456;
    if (i < 147456) { int n = i / 768, k = i % 768; w2T[i] = f2bf(w2[k * 192 + n]); return; }
    i -= 147456;
    if (i < 57624) {
        int h = i / 9604, rm = i % 9604, n = rm / 98, m = rm % 98;
        int tdn = n / 49, thn = (n / 7) % 7, twn = n % 7;
        int tdm = m / 49, thm = (m / 7) % 7, twm = m % 7;
        int idx = (tdn - tdm + 1) * 169 + (thn - thm + 6) * 13 + (twn - twm + 6);
        bias6[i] = relb[idx * 6 + h];
    }
}

// ---------- stats: per-token LN mean/rstd over fp32 [tok][192] ----------
__global__ __launch_bounds__(256) void stats_f32_k(const float* __restrict__ x,
    float* __restrict__ st)
{
    int tok = blockIdx.x * 4 + (threadIdx.x >> 6);
    int lane = threadIdx.x & 63;
    const float* p = x + (size_t)tok * 192;
    float a = p[lane], b = p[64 + lane], c = p[128 + lane];
    float s = a + b + c, q = a * a + b * b + c * c;
    for (int m = 32; m; m >>= 1) { s += __shfl_xor(s, m); q += __shfl_xor(q, m); }
    if (lane == 0) {
        float mean = s * (1.f / 192.f);
        float var  = q * (1.f / 192.f) - mean * mean;
        st[2 * tok] = mean;
        st[2 * tok + 1] = rsqrtf(var + 1e-6f);
    }
}

// ---------- GEMM: C[M][N] = A[M][K](bf16) * BT[N][K]^T(bf16) + epilogue ----------
// 64x64 tile, 4 waves 2x2. N-blocks on blockIdx.x (fast) -> consecutive blocks
// share the same A-panel => A (and the fp32 x gather) is L2-hit after first use.
// STAGE: 0 = A is plain bf16 [M][K] chunk-local rows
//        1 = A is virtual modulate(LN(x)) via window gather; Af = x fp32, stats=stats1
//        2 = A is virtual modulate(LN(x1)); Af = x1 fp32 at global rows row0+g, stats=stats2
// EPI:   0 = bias -> bf16 outB (qkv chunk)
//        1 = bias + gelu -> bf16 outB (fc1 chunk)
//        2 = proj: scatter-residual -> fp32 outF (x1 = auxF + g*v), auxF = x fp32
//        3 = fc2: in-place final residual on fp32 outF at global rows
template<int STAGE, int EPI>
__global__ __launch_bounds__(256) void gemm_k(
    const unsigned short* __restrict__ A, const float* __restrict__ Af,
    const unsigned short* __restrict__ BT, const float* __restrict__ bias,
    unsigned short* __restrict__ outB, float* outF,
    const float* __restrict__ auxF, const float* __restrict__ stats,
    const float* __restrict__ mod, int row0, int M, int N, int K)
{
    __shared__ unsigned short As[64][56];   // row stride 112B
    __shared__ unsigned short Bs[64][56];
    const int t = threadIdx.x;
    const int n0 = blockIdx.x * 64, m0 = blockIdx.y * 64;
    const int lr = t >> 2, lk = (t & 3) * 8;
    const int wid = t >> 6, lane = t & 63;
    const int lg = lane >> 4, l16 = lane & 15;
    const int wm = (wid >> 1) * 32, wn = (wid & 1) * 32;
    f32x4 acc[2][2] = {};

    // hoisted per-row staging state
    const int g = m0 + lr;   // chunk-local row this thread stages
    bool v1 = false; size_t sbase = 0; float mn = 0.f, rs = 0.f;
    if (STAGE == 1) {
        int T;
        if (g < M && winmapT(row0 + g, T)) {
            v1 = true; sbase = (size_t)T * 192;
            mn = stats[2 * T]; rs = stats[2 * T + 1];
        }
    } else if (STAGE == 2) {
        int tok = row0 + g;
        sbase = (size_t)tok * 192;
        mn = stats[2 * tok]; rs = stats[2 * tok + 1];
    }

    for (int kk = 0; kk < K; kk += 32) {
        if (STAGE == 0) {
            u16x8 av = {0, 0, 0, 0, 0, 0, 0, 0};
            if (g < M) av = *(const u16x8*)(A + (size_t)g * K + kk + lk);
            *(u16x8*)(&As[lr][lk]) = av;
        } else if (STAGE == 1) {
            u16x8 o = {0, 0, 0, 0, 0, 0, 0, 0};
            if (v1) {
                float4 xa = *(const float4*)(Af + sbase + kk + lk);
                float4 xb = *(const float4*)(Af + sbase + kk + lk + 4);
                float xs[8] = {xa.x, xa.y, xa.z, xa.w, xb.x, xb.y, xb.z, xb.w};
                #pragma unroll
                for (int j = 0; j < 8; ++j) {
                    int c = kk + lk + j;
                    o[j] = f2bf((xs[j] - mn) * rs * (1.f + mod[192 + c]) + mod[c]);
                }
            }
            *(u16x8*)(&As[lr][lk]) = o;
        } else { // STAGE 2: modulate(LN2(x1)) from fp32 x1
            float4 xa = *(const float4*)(Af + sbase + kk + lk);
            float4 xb = *(const float4*)(Af + sbase + kk + lk + 4);
            float xs[8] = {xa.x, xa.y, xa.z, xa.w, xb.x, xb.y, xb.z, xb.w};
            u16x8 o;
            #pragma unroll
            for (int j = 0; j < 8; ++j) {
                int c = kk + lk + j;
                o[j] = f2bf((xs[j] - mn) * rs * (1.f + mod[768 + c]) + mod[576 + c]);
            }
            *(u16x8*)(&As[lr][lk]) = o;
        }
        u16x8 bv = *(const u16x8*)(BT + (size_t)(n0 + lr) * K + kk + lk);
        *(u16x8*)(&Bs[lr][lk]) = bv;
        __syncthreads();
        bf16x8 af0 = load8(&As[wm + l16][4 * lg]);
        bf16x8 af1 = load8(&As[wm + 16 + l16][4 * lg]);
        bf16x8 bf0 = load8(&Bs[wn + l16][4 * lg]);
        bf16x8 bf1 = load8(&Bs[wn + 16 + l16][4 * lg]);
        acc[0][0] = mfma16(af0, bf0, acc[0][0]);
        acc[0][1] = mfma16(af0, bf1, acc[0][1]);
        acc[1][0] = mfma16(af1, bf0, acc[1][0]);
        acc[1][1] = mfma16(af1, bf1, acc[1][1]);
        __syncthreads();
    }

    #pragma unroll
    for (int i = 0; i < 2; ++i)
    #pragma unroll
    for (int j = 0; j < 2; ++j) {
        int gcol = n0 + wn + j * 16 + l16;
        float b = bias[gcol];
        #pragma unroll
        for (int e = 0; e < 4; ++e) {
            int grow = m0 + wm + i * 16 + lg * 4 + e;   // chunk-local
            if (grow >= M) continue;
            float v = acc[i][j][e] + b;
            if (EPI == 0) {
                outB[(size_t)grow * N + gcol] = f2bf(v);
            } else if (EPI == 1) {
                float gl = 0.5f * v * (1.f + erff(v * 0.70710678118654752f));
                outB[(size_t)grow * N + gcol] = f2bf(gl);
            } else if (EPI == 2) {
                int T;
                if (winmapT(row0 + grow, T)) {
                    size_t idx = (size_t)T * 192 + gcol;
                    outF[idx] = auxF[idx] + mod[384 + gcol] * v;
                }
            } else {
                size_t idx = (size_t)(row0 + grow) * 192 + gcol;
                outF[idx] = outF[idx] + mod[960 + gcol] * v;
            }
        }
    }
}

// ---------- attention: one block per (local window, head), in-register softmax ----------
// LDS 38.3 KB -> 4 blocks/CU. S never touches LDS; row reduce via 16-lane shfl.
__global__ __launch_bounds__(256) void attn_k(
    const unsigned short* __restrict__ qkv, const float* __restrict__ mask,
    const float* __restrict__ bias6, unsigned short* __restrict__ out)
{
    __shared__ __align__(16) char smem[39168];
    unsigned short* Qs  = (unsigned short*)smem;            // [112][40]  (phase 1-2)
    unsigned short* Ks  = (unsigned short*)(smem + 8960);   // [112][40]  (phase 1-2)
    unsigned short* Pbf = (unsigned short*)smem;            // [112][136] (phase 3-4, aliases Qs/Ks)
    unsigned short* VT  = (unsigned short*)(smem + 30464);  // [32][136]

    const int blk = blockIdx.x;
    const int win = blk / 6, h = blk % 6;   // local window id
    const int t = threadIdx.x;
    const int wid = t >> 6, lg = (t >> 4) & 3, l16 = t & 15;
    const size_t rb = (size_t)win * 98;

    // ---- phase 1: stage Q,K rows ([98][32] + zero pad rows) and V^T ----
    for (int i = t; i < 98 * 4; i += 256) {
        int r = i >> 2, cg = (i & 3) * 8;
        *(float4*)(Qs + r * 40 + cg) = *(const float4*)(qkv + (rb + r) * 576 + h * 32 + cg);
        *(float4*)(Ks + r * 40 + cg) = *(const float4*)(qkv + (rb + r) * 576 + 192 + h * 32 + cg);
    }
    for (int i = t; i < 14 * 32; i += 256) {
        int r = 98 + (i >> 5), c = i & 31;
        Qs[r * 40 + c] = 0; Ks[r * 40 + c] = 0;
    }
    for (int i = t; i < 32 * 38; i += 256) { int c = i / 38, m = 98 + i % 38; VT[c * 136 + m] = 0; }
    for (int i = t; i < 98 * 32; i += 256) {
        int m = i >> 5, c = i & 31;
        VT[c * 136 + m] = qkv[(rb + m) * 576 + 384 + h * 32 + c];
    }
    __syncthreads();

    // ---- phase 2: S = Q K^T, fragments stay in registers ----
    f32x4 acc[2][7];
    {
        bf16x8 kb[7];
        #pragma unroll
        for (int fn = 0; fn < 7; ++fn) kb[fn] = load8(Ks + (fn * 16 + l16) * 40 + 4 * lg);
        #pragma unroll
        for (int fi = 0; fi < 2; ++fi) {
            int fm = wid + fi * 4;
            if (fm < 7) {
                bf16x8 qa = load8(Qs + (fm * 16 + l16) * 40 + 4 * lg);
                #pragma unroll
                for (int fn = 0; fn < 7; ++fn) {
                    f32x4 z = {};
                    acc[fi][fn] = mfma16(qa, kb[fn], z);
                }
            }
        }
    }
    __syncthreads();   // Qs/Ks dead; Pbf region may now be written

    // ---- phase 3: in-register softmax (scale + bias + mask, row reduce over l16 group) ----
    const float SCALE = 0.17677669529663687f;
    float rinv[2][4];
    #pragma unroll
    for (int fi = 0; fi < 2; ++fi) {
        int fm = wid + fi * 4;
        if (fm < 7) {
            #pragma unroll
            for (int e = 0; e < 4; ++e) {
                int r = fm * 16 + lg * 4 + e;
                float mx = -1e30f;
                #pragma unroll
                for (int fn = 0; fn < 7; ++fn) {
                    int c = fn * 16 + l16;
                    float s = -1e30f;
                    if (r < 98 && c < 98) {
                        float bm = bias6[(size_t)h * 9604 + r * 98 + c]
                                 + mask[(size_t)win * 9604 + r * 98 + c];
                        s = fmaf(acc[fi][fn][e], SCALE, bm);
                    }
                    acc[fi][fn][e] = s;
                    mx = fmaxf(mx, s);
                }
                #pragma unroll
                for (int m = 1; m < 16; m <<= 1) mx = fmaxf(mx, __shfl_xor(mx, m));
                float sum = 0.f;
                #pragma unroll
                for (int fn = 0; fn < 7; ++fn) {
                    float p = __expf(acc[fi][fn][e] - mx);
                    acc[fi][fn][e] = p;
                    sum += p;
                }
                #pragma unroll
                for (int m = 1; m < 16; m <<= 1) sum += __shfl_xor(sum, m);
                rinv[fi][e] = 1.f / sum;
            }
            // write P (bf16) in A-fragment-consumable layout
            #pragma unroll
            for (int fn = 0; fn < 7; ++fn) {
                int c = fn * 16 + l16;
                #pragma unroll
                for (int e = 0; e < 4; ++e) {
                    int r = fm * 16 + lg * 4 + e;
                    float val = (r < 98 && c < 98) ? acc[fi][fn][e] : 0.f;
                    Pbf[r * 136 + c] = f2bf(val);
                }
            }
        }
    }
    // zero P cols 112..127 (never covered by fragment writes)
    for (int i = t; i < 112 * 8; i += 256) {
        int r = i >> 3, c = 112 + (i & 7) * 2;
        *(unsigned int*)(Pbf + r * 136 + c) = 0u;
    }
    __syncthreads();

    // ---- phase 4: O = P V (K padded to 128), divide by in-register row sums ----
    #pragma unroll
    for (int fi = 0; fi < 2; ++fi) {
        int fm = wid + fi * 4;
        if (fm < 7) {
            bf16x8 sa[4];
            #pragma unroll
            for (int ks = 0; ks < 4; ++ks)
                sa[ks] = load8(Pbf + (fm * 16 + l16) * 136 + ks * 32 + 4 * lg);
            #pragma unroll
            for (int fn = 0; fn < 2; ++fn) {
                f32x4 o = {};
                #pragma unroll
                for (int ks = 0; ks < 4; ++ks) {
                    bf16x8 vb = load8(VT + (fn * 16 + l16) * 136 + ks * 32 + 4 * lg);
                    o = mfma16(sa[ks], vb, o);
                }
                #pragma unroll
                for (int e = 0; e < 4; ++e) {
                    int r = fm * 16 + lg * 4 + e;
                    if (r < 98) {
                        out[(rb + r) * 192 + h * 32 + fn * 16 + l16] = f2bf(o[e] * rinv[fi][e]);
                    }
                }
            }
        }
    }
}

// ---------- launch ----------
// d_out is fp32 [131072][192]; it is ALSO the x1 buffer (proj writes x1 there,
// fc2 does the in-place final residual). Workspace span ~35.5 MB.
extern "C" void kernel_launch(void* const* d_in, const int* in_sizes, int n_in,
                              void* d_out, int out_size, void* d_ws, size_t ws_size,
                              hipStream_t stream)
{
    const float* x      = (const float*)d_in[0];
    const float* maskm  = (const float*)d_in[1];
    const float* tvec   = (const float*)d_in[2];
    const float* w_qkv  = (const float*)d_in[3];
    const float* b_qkv  = (const float*)d_in[4];
    const float* relb   = (const float*)d_in[5];
    const float* w_proj = (const float*)d_in[6];
    const float* b_proj = (const float*)d_in[7];
    const float* w1     = (const float*)d_in[8];
    const float* b1     = (const float*)d_in[9];
    const float* w2     = (const float*)d_in[10];
    const float* b2     = (const float*)d_in[11];
    const float* wa1    = (const float*)d_in[12];
    const float* wa2    = (const float*)d_in[13];
    const float* ba2    = (const float*)d_in[14];

    char* ws = (char*)d_ws;
    float*          mod    = (float*)ws;
    float*          stats1 = (float*)(ws + 4608);
    float*          stats2 = (float*)(ws + 1053184);
    unsigned short* wqkvT  = (unsigned short*)(ws + 2101760);
    unsigned short* wprojT = (unsigned short*)(ws + 2322944);
    unsigned short* w1T    = (unsigned short*)(ws + 2396672);
    unsigned short* w2T    = (unsigned short*)(ws + 2691584);
    float*          bias6  = (float*)(ws + 2986496);
    unsigned short* qkvb_c = (unsigned short*)(ws + 3216992);   // [18620][576] bf16
    unsigned short* hq_c   = (unsigned short*)(ws + 3216992);   // [16384][768] bf16 (aliases)
    unsigned short* attn_c = (unsigned short*)(ws + 28382816);  // [18620][192] bf16
    float*          dout   = (float*)d_out;                     // fp32 out == x1 buffer

    mod_k<<<1, 256, 0, stream>>>(tvec, wa1, wa2, ba2, mod);
    prep_k<<<1954, 256, 0, stream>>>(w_qkv, w_proj, w1, w2, relb, wqkvT, wprojT, w1T, w2T, bias6);
    stats_f32_k<<<32768, 256, 0, stream>>>(x, stats1);

    // qkv -> attention -> proj(+residual scatter into d_out as fp32 x1), 8 window-chunks
    for (int wc = 0; wc < 8; ++wc) {
        int r0 = wc * 18620;
        gemm_k<1, 0><<<dim3(9, 291), 256, 0, stream>>>(
            nullptr, x, wqkvT, b_qkv, qkvb_c, nullptr, nullptr, stats1, mod, r0, 18620, 576, 192);
        attn_k<<<1140, 256, 0, stream>>>(qkvb_c, maskm + (size_t)wc * 190 * 9604, bias6, attn_c);
        gemm_k<0, 2><<<dim3(3, 291), 256, 0, stream>>>(
            attn_c, nullptr, wprojT, b_proj, nullptr, dout, x, nullptr, mod, r0, 18620, 192, 192);
    }

    stats_f32_k<<<32768, 256, 0, stream>>>(dout, stats2);

    // MLP: fc1(+LN2 fused staging, gelu) -> fc2(in-place final residual on d_out), 8 chunks
    for (int q = 0; q < 8; ++q) {
        int r0 = q * 16384;
        gemm_k<2, 1><<<dim3(12, 256), 256, 0, stream>>>(
            nullptr, dout, w1T, b1, hq_c, nullptr, nullptr, stats2, mod, r0, 16384, 768, 192);
        gemm_k<0, 3><<<dim3(3, 256), 256, 0, stream>>>(
            hq_c, nullptr, w2T, b2, nullptr, dout, nullptr, nullptr, mod, r0, 16384, 192, 768);
    }
}

// Round 6
// 1411.131 us; speedup vs baseline: 1.0346x; 1.0346x over previous
//
#include <hip/hip_runtime.h>
#include <hip/hip_bf16.h>

// ---------- types ----------
typedef __bf16 bf16x8 __attribute__((ext_vector_type(8)));
typedef float  f32x4  __attribute__((ext_vector_type(4)));
typedef unsigned int u32x4 __attribute__((ext_vector_type(4)));

__device__ inline unsigned short f2bf(float f) {
    union { __hip_bfloat16 h; unsigned short u; } cv;
    cv.h = __float2bfloat16(f);
    return cv.u;
}

// load 8 bf16 = two 8B halves at col +0 and col +16 (k-halves of 16x16x32)
__device__ inline bf16x8 load8(const unsigned short* p) {
    uint2 lo = *(const uint2*)(p);
    uint2 hi = *(const uint2*)(p + 16);
    u32x4 v; v[0] = lo.x; v[1] = lo.y; v[2] = hi.x; v[3] = hi.y;
    return __builtin_bit_cast(bf16x8, v);
}

__device__ inline f32x4 mfma16(bf16x8 a, bf16x8 b, f32x4 c) {
    return __builtin_amdgcn_mfma_f32_16x16x32_bf16(a, b, c, 0, 0, 0);
}

// window-row (global, 0..148959) -> spatial token (0..131071); false if pad
__device__ inline bool winmapT(int gg, int& T) {
    int win = gg / 98, n = gg % 98;
    int wdi = win / 190, rem = win % 190, whi = rem / 19, wwi = rem % 19;
    int td = n / 49, th = (n / 7) % 7, tw = n % 7;
    int sd = (wdi * 2 + td + 1) & 15;
    int sh = whi * 7 + th + 3; if (sh >= 70) sh -= 70;
    int sw = wwi * 7 + tw + 3; if (sw >= 133) sw -= 133;
    if (sh < 64 && sw < 128) { T = (sd * 64 + sh) * 128 + sw; return true; }
    return false;
}

// ---------- K0: mod = silu(t) @ wa1 @ wa2 + ba2  (1152 floats) ----------
__global__ __launch_bounds__(256) void mod_k(const float* __restrict__ t,
    const float* __restrict__ wa1, const float* __restrict__ wa2,
    const float* __restrict__ ba2, float* __restrict__ mod)
{
    __shared__ float st[192];
    __shared__ float a[24];
    int tid = threadIdx.x;
    if (tid < 192) { float x = t[tid]; st[tid] = x / (1.f + __expf(-x)); }
    __syncthreads();
    if (tid < 24) {
        float s = 0.f;
        for (int c = 0; c < 192; ++c) s += st[c] * wa1[c * 24 + tid];
        a[tid] = s;
    }
    __syncthreads();
    for (int j = tid; j < 1152; j += 256) {
        float s = ba2[j];
        for (int r = 0; r < 24; ++r) s += a[r] * wa2[r * 1152 + j];
        mod[j] = s;
    }
}

// ---------- K1: weight transposes (fp32 -> bf16, [N][K]) + fused bias+mask table ----------
// btab[(mt*6+h)*9604 + n*98 + m] = rel_bias(h,n,m) + mask(mt,n,m)
// mt bit0: d-boundary window (wdi==7), bit1: h-boundary (whi==9), bit2: w-boundary (wwi==18)
__global__ __launch_bounds__(256) void prep_k(
    const float* __restrict__ wqkv, const float* __restrict__ wproj,
    const float* __restrict__ w1, const float* __restrict__ w2,
    const float* __restrict__ relb,
    unsigned short* __restrict__ wqkvT, unsigned short* __restrict__ wprojT,
    unsigned short* __restrict__ w1T, unsigned short* __restrict__ w2T,
    float* __restrict__ btab)
{
    int i = blockIdx.x * 256 + threadIdx.x;
    if (i < 110592) { int n = i / 192, k = i % 192; wqkvT[i] = f2bf(wqkv[k * 576 + n]); return; }
    i -= 110592;
    if (i < 36864)  { int n = i / 192, k = i % 192; wprojT[i] = f2bf(wproj[k * 192 + n]); return; }
    i -= 36864;
    if (i < 147456) { int n = i / 192, k = i % 192; w1T[i] = f2bf(w1[k * 768 + n]); return; }
    i -= 147456;
    if (i < 147456) { int n = i / 768, k = i % 768; w2T[i] = f2bf(w2[k * 192 + n]); return; }
    i -= 147456;
    if (i < 461952) {
        int mt = i / 57624, rem = i % 57624;
        int h = rem / 9604, rm2 = rem % 9604;
        int n = rm2 / 98, m = rm2 % 98;
        int tdn = n / 49, thn = (n / 7) % 7, twn = n % 7;
        int tdm = m / 49, thm = (m / 7) % 7, twm = m % 7;
        int idx = (tdn - tdm + 1) * 169 + (thn - thm + 6) * 13 + (twn - twm + 6);
        float b = relb[idx * 6 + h];
        int bd = mt & 1, bh = (mt >> 1) & 1, bw = (mt >> 2) & 1;
        // region ids on the padded grid: d: [0,14)|14|15 ; h: [0,63)|[63,67)|[67,70) ; w: [0,126)|[126,130)|[130,133)
        int idn = (bd ? (tdn == 0 ? 1 : 2) : 0) * 9 + (bh ? (thn < 4 ? 1 : 2) : 0) * 3 + (bw ? (twn < 4 ? 1 : 2) : 0);
        int idm = (bd ? (tdm == 0 ? 1 : 2) : 0) * 9 + (bh ? (thm < 4 ? 1 : 2) : 0) * 3 + (bw ? (twm < 4 ? 1 : 2) : 0);
        btab[i] = b + ((idn != idm) ? -100.f : 0.f);
    }
}

// ---------- stats: per-token LN mean/rstd over fp32 [tok][192] ----------
__global__ __launch_bounds__(256) void stats_f32_k(const float* __restrict__ x,
    float* __restrict__ st)
{
    int tok = blockIdx.x * 4 + (threadIdx.x >> 6);
    int lane = threadIdx.x & 63;
    const float* p = x + (size_t)tok * 192;
    float a = p[lane], b = p[64 + lane], c = p[128 + lane];
    float s = a + b + c, q = a * a + b * b + c * c;
    for (int m = 32; m; m >>= 1) { s += __shfl_xor(s, m); q += __shfl_xor(q, m); }
    if (lane == 0) {
        float mean = s * (1.f / 192.f);
        float var  = q * (1.f / 192.f) - mean * mean;
        st[2 * tok] = mean;
        st[2 * tok + 1] = rsqrtf(var + 1e-6f);
    }
}

// ---------- GEMM: C[M][N] = A[M][K](bf16) * BT[N][K]^T(bf16) + epilogue ----------
// 128 x (FN*32) tile, 4 waves 2x2; wave = 64 x FN*16 via 4 x FN frags of 16x16x32.
// LDS row stride 44 shorts (88B, odd-dword-pair) -> ~4-way max on b64 reads.
// STAGE: 0 = A plain bf16 [M][K] chunk rows; 1 = virtual modulate(LN(x)) window gather;
//        2 = virtual modulate(LN(x1)) from fp32 x1 at rows row0+g
// EPI:   0 = bias->bf16; 1 = bias+gelu->bf16; 2 = proj scatter residual->fp32 out;
//        3 = fc2 in-place final residual on fp32 out
template<int FN, int STAGE, int EPI>
__global__ __launch_bounds__(256) void gemm_k(
    const unsigned short* __restrict__ A, const float* __restrict__ Af,
    const unsigned short* __restrict__ BT, const float* __restrict__ bias,
    unsigned short* __restrict__ outB, float* outF,
    const float* __restrict__ auxF, const float* __restrict__ stats,
    const float* __restrict__ mod, int row0, int M, int N, int K)
{
    constexpr int BN = FN * 32;
    __shared__ unsigned short As[128][44];
    __shared__ unsigned short Bs[BN][44];
    const int t = threadIdx.x;
    const int n0 = blockIdx.x * BN, m0 = blockIdx.y * 128;
    const int lr = t >> 2, lk = (t & 3) * 8;
    const int wid = t >> 6, lane = t & 63;
    const int lg = lane >> 4, l16 = lane & 15;
    const int wm = (wid >> 1) * 64, wn = (wid & 1) * (FN * 16);
    f32x4 acc[4][FN] = {};

    // per-row staging state for rows lr and lr+64
    float mn[2] = {0.f, 0.f}, rs[2] = {0.f, 0.f};
    size_t sbase[2] = {0, 0};
    bool va[2] = {false, false};
    #pragma unroll
    for (int rr = 0; rr < 2; ++rr) {
        int g = m0 + lr + rr * 64;
        if (STAGE == 1) {
            int T;
            if (g < M && winmapT(row0 + g, T)) {
                va[rr] = true; sbase[rr] = (size_t)T * 192;
                mn[rr] = stats[2 * T]; rs[rr] = stats[2 * T + 1];
            }
        } else if (STAGE == 2) {
            int tok = row0 + g;
            sbase[rr] = (size_t)tok * 192;
            mn[rr] = stats[2 * tok]; rs[rr] = stats[2 * tok + 1];
        }
    }

    for (int kk = 0; kk < K; kk += 32) {
        #pragma unroll
        for (int rr = 0; rr < 2; ++rr) {
            int r = lr + rr * 64;
            int g = m0 + r;
            uint4 w = make_uint4(0u, 0u, 0u, 0u);
            if (STAGE == 0) {
                if (g < M) w = *(const uint4*)(A + (size_t)g * K + kk + lk);
            } else if (STAGE == 1) {
                if (va[rr]) {
                    float4 xa = *(const float4*)(Af + sbase[rr] + kk + lk);
                    float4 xb = *(const float4*)(Af + sbase[rr] + kk + lk + 4);
                    float xs[8] = {xa.x, xa.y, xa.z, xa.w, xb.x, xb.y, xb.z, xb.w};
                    unsigned short o[8];
                    #pragma unroll
                    for (int j = 0; j < 8; ++j) {
                        int c = kk + lk + j;
                        o[j] = f2bf((xs[j] - mn[rr]) * rs[rr] * (1.f + mod[192 + c]) + mod[c]);
                    }
                    w = make_uint4((unsigned)o[0] | ((unsigned)o[1] << 16), (unsigned)o[2] | ((unsigned)o[3] << 16),
                                   (unsigned)o[4] | ((unsigned)o[5] << 16), (unsigned)o[6] | ((unsigned)o[7] << 16));
                }
            } else { // STAGE 2
                float4 xa = *(const float4*)(Af + sbase[rr] + kk + lk);
                float4 xb = *(const float4*)(Af + sbase[rr] + kk + lk + 4);
                float xs[8] = {xa.x, xa.y, xa.z, xa.w, xb.x, xb.y, xb.z, xb.w};
                unsigned short o[8];
                #pragma unroll
                for (int j = 0; j < 8; ++j) {
                    int c = kk + lk + j;
                    o[j] = f2bf((xs[j] - mn[rr]) * rs[rr] * (1.f + mod[768 + c]) + mod[576 + c]);
                }
                w = make_uint4((unsigned)o[0] | ((unsigned)o[1] << 16), (unsigned)o[2] | ((unsigned)o[3] << 16),
                               (unsigned)o[4] | ((unsigned)o[5] << 16), (unsigned)o[6] | ((unsigned)o[7] << 16));
            }
            *(uint2*)(&As[r][lk])     = make_uint2(w.x, w.y);
            *(uint2*)(&As[r][lk + 4]) = make_uint2(w.z, w.w);
        }
        #pragma unroll
        for (int rr = 0; rr < BN / 64; ++rr) {
            int r = lr + rr * 64;
            int gn = n0 + r;
            uint4 w = make_uint4(0u, 0u, 0u, 0u);
            if (gn < N) w = *(const uint4*)(BT + (size_t)gn * K + kk + lk);
            *(uint2*)(&Bs[r][lk])     = make_uint2(w.x, w.y);
            *(uint2*)(&Bs[r][lk + 4]) = make_uint2(w.z, w.w);
        }
        __syncthreads();
        bf16x8 af[4], bv[FN];
        #pragma unroll
        for (int i = 0; i < 4; ++i) af[i] = load8(&As[wm + i * 16 + l16][4 * lg]);
        #pragma unroll
        for (int j = 0; j < FN; ++j) bv[j] = load8(&Bs[wn + j * 16 + l16][4 * lg]);
        #pragma unroll
        for (int i = 0; i < 4; ++i)
        #pragma unroll
        for (int j = 0; j < FN; ++j)
            acc[i][j] = mfma16(af[i], bv[j], acc[i][j]);
        __syncthreads();
    }

    #pragma unroll
    for (int i = 0; i < 4; ++i)
    #pragma unroll
    for (int j = 0; j < FN; ++j) {
        int gcol = n0 + wn + j * 16 + l16;
        if (gcol >= N) continue;
        float b = bias[gcol];
        #pragma unroll
        for (int e = 0; e < 4; ++e) {
            int grow = m0 + wm + i * 16 + lg * 4 + e;   // chunk-local
            if (grow >= M) continue;
            float v = acc[i][j][e] + b;
            if (EPI == 0) {
                outB[(size_t)grow * N + gcol] = f2bf(v);
            } else if (EPI == 1) {
                float gl = 0.5f * v * (1.f + erff(v * 0.70710678118654752f));
                outB[(size_t)grow * N + gcol] = f2bf(gl);
            } else if (EPI == 2) {
                int T;
                if (winmapT(row0 + grow, T)) {
                    size_t idx = (size_t)T * 192 + gcol;
                    outF[idx] = auxF[idx] + mod[384 + gcol] * v;
                }
            } else {
                size_t idx = (size_t)(row0 + grow) * 192 + gcol;
                outF[idx] = outF[idx] + mod[960 + gcol] * v;
            }
        }
    }
}

// ---------- attention: one block per (local window, head), in-register softmax ----------
// btab is the fused (rel_bias + mask) table: 48 x 9604 fp32, L2-resident.
__global__ __launch_bounds__(256) void attn_k(
    const unsigned short* __restrict__ qkv, const float* __restrict__ btab,
    unsigned short* __restrict__ out, int winBase)
{
    __shared__ __align__(16) char smem[40320];
    unsigned short* Qs  = (unsigned short*)smem;            // [112][44]  (phase 1-2)
    unsigned short* Ks  = (unsigned short*)(smem + 9856);   // [112][44]  (phase 1-2)
    unsigned short* Pbf = (unsigned short*)smem;            // [112][140] (phase 3-4, aliases Qs/Ks)
    unsigned short* VT  = (unsigned short*)(smem + 31360);  // [32][140]

    const int blk = blockIdx.x;
    const int win = blk / 6, h = blk % 6;   // local window id
    const int t = threadIdx.x;
    const int wid = t >> 6, lg = (t >> 4) & 3, l16 = t & 15;
    const size_t rb = (size_t)win * 98;

    // fused bias+mask row base for this (window-type, head)
    const int wg = winBase + win;
    const int wdi = wg / 190, remw = wg % 190, whi = remw / 19, wwi = remw % 19;
    const int mt = (wdi == 7 ? 1 : 0) | (whi == 9 ? 2 : 0) | (wwi == 18 ? 4 : 0);
    const float* bt = btab + (size_t)(mt * 6 + h) * 9604;

    // ---- phase 1: stage Q,K rows ([98][32] + zero pad rows) and V^T ----
    for (int i = t; i < 98 * 4; i += 256) {
        int r = i >> 2, cg = (i & 3) * 8;
        uint4 q = *(const uint4*)(qkv + (rb + r) * 576 + h * 32 + cg);
        uint4 k = *(const uint4*)(qkv + (rb + r) * 576 + 192 + h * 32 + cg);
        *(uint2*)(Qs + r * 44 + cg)     = make_uint2(q.x, q.y);
        *(uint2*)(Qs + r * 44 + cg + 4) = make_uint2(q.z, q.w);
        *(uint2*)(Ks + r * 44 + cg)     = make_uint2(k.x, k.y);
        *(uint2*)(Ks + r * 44 + cg + 4) = make_uint2(k.z, k.w);
    }
    for (int i = t; i < 14 * 32; i += 256) {
        int r = 98 + (i >> 5), c = i & 31;
        Qs[r * 44 + c] = 0; Ks[r * 44 + c] = 0;
    }
    for (int i = t; i < 32 * 42; i += 256) { int c = i / 42, m = 98 + i % 42; VT[c * 140 + m] = 0; }
    for (int i = t; i < 98 * 32; i += 256) {
        int m = i >> 5, c = i & 31;
        VT[c * 140 + m] = qkv[(rb + m) * 576 + 384 + h * 32 + c];
    }
    __syncthreads();

    // ---- phase 2: S = Q K^T, fragments stay in registers ----
    f32x4 acc[2][7];
    {
        bf16x8 kb[7];
        #pragma unroll
        for (int fn = 0; fn < 7; ++fn) kb[fn] = load8(Ks + (fn * 16 + l16) * 44 + 4 * lg);
        #pragma unroll
        for (int fi = 0; fi < 2; ++fi) {
            int fm = wid + fi * 4;
            if (fm < 7) {
                bf16x8 qa = load8(Qs + (fm * 16 + l16) * 44 + 4 * lg);
                #pragma unroll
                for (int fn = 0; fn < 7; ++fn) {
                    f32x4 z = {};
                    acc[fi][fn] = mfma16(qa, kb[fn], z);
                }
            }
        }
    }
    __syncthreads();   // Qs/Ks dead; Pbf region may now be written

    // ---- phase 3: in-register softmax (scale + fused bias/mask, 16-lane row reduce) ----
    const float SCALE = 0.17677669529663687f;
    float rinv[2][4];
    #pragma unroll
    for (int fi = 0; fi < 2; ++fi) {
        int fm = wid + fi * 4;
        if (fm < 7) {
            #pragma unroll
            for (int e = 0; e < 4; ++e) {
                int r = fm * 16 + lg * 4 + e;
                float mx = -1e30f;
                #pragma unroll
                for (int fn = 0; fn < 7; ++fn) {
                    int c = fn * 16 + l16;
                    float s = -1e30f;
                    if (r < 98 && c < 98) s = fmaf(acc[fi][fn][e], SCALE, bt[r * 98 + c]);
                    acc[fi][fn][e] = s;
                    mx = fmaxf(mx, s);
                }
                #pragma unroll
                for (int m = 1; m < 16; m <<= 1) mx = fmaxf(mx, __shfl_xor(mx, m));
                float sum = 0.f;
                #pragma unroll
                for (int fn = 0; fn < 7; ++fn) {
                    float p = __expf(acc[fi][fn][e] - mx);
                    acc[fi][fn][e] = p;
                    sum += p;
                }
                #pragma unroll
                for (int m = 1; m < 16; m <<= 1) sum += __shfl_xor(sum, m);
                rinv[fi][e] = 1.f / sum;
            }
            #pragma unroll
            for (int fn = 0; fn < 7; ++fn) {
                int c = fn * 16 + l16;
                #pragma unroll
                for (int e = 0; e < 4; ++e) {
                    int r = fm * 16 + lg * 4 + e;
                    float val = (r < 98 && c < 98) ? acc[fi][fn][e] : 0.f;
                    Pbf[r * 140 + c] = f2bf(val);
                }
            }
        }
    }
    // zero P cols 112..127 (never covered by fragment writes)
    for (int i = t; i < 112 * 8; i += 256) {
        int r = i >> 3, c = 112 + (i & 7) * 2;
        *(unsigned int*)(Pbf + r * 140 + c) = 0u;
    }
    __syncthreads();

    // ---- phase 4: O = P V (K padded to 128), divide by in-register row sums ----
    #pragma unroll
    for (int fi = 0; fi < 2; ++fi) {
        int fm = wid + fi * 4;
        if (fm < 7) {
            bf16x8 sa[4];
            #pragma unroll
            for (int ks = 0; ks < 4; ++ks)
                sa[ks] = load8(Pbf + (fm * 16 + l16) * 140 + ks * 32 + 4 * lg);
            #pragma unroll
            for (int fn = 0; fn < 2; ++fn) {
                f32x4 o = {};
                #pragma unroll
                for (int ks = 0; ks < 4; ++ks) {
                    bf16x8 vb = load8(VT + (fn * 16 + l16) * 140 + ks * 32 + 4 * lg);
                    o = mfma16(sa[ks], vb, o);
                }
                #pragma unroll
                for (int e = 0; e < 4; ++e) {
                    int r = fm * 16 + lg * 4 + e;
                    if (r < 98) {
                        out[(rb + r) * 192 + h * 32 + fn * 16 + l16] = f2bf(o[e] * rinv[fi][e]);
                    }
                }
            }
        }
    }
}

// ---------- launch ----------
// d_out is fp32 [131072][192]; it is ALSO the x1 buffer. Workspace span ~35.4 MB.
extern "C" void kernel_launch(void* const* d_in, const int* in_sizes, int n_in,
                              void* d_out, int out_size, void* d_ws, size_t ws_size,
                              hipStream_t stream)
{
    const float* x      = (const float*)d_in[0];
    const float* tvec   = (const float*)d_in[2];
    const float* w_qkv  = (const float*)d_in[3];
    const float* b_qkv  = (const float*)d_in[4];
    const float* relb   = (const float*)d_in[5];
    const float* w_proj = (const float*)d_in[6];
    const float* b_proj = (const float*)d_in[7];
    const float* w1     = (const float*)d_in[8];
    const float* b1     = (const float*)d_in[9];
    const float* w2     = (const float*)d_in[10];
    const float* b2     = (const float*)d_in[11];
    const float* wa1    = (const float*)d_in[12];
    const float* wa2    = (const float*)d_in[13];
    const float* ba2    = (const float*)d_in[14];

    char* ws = (char*)d_ws;
    float*          mod    = (float*)ws;                        // 4,608
    float*          stats1 = (float*)(ws + 4608);               // 1,048,576
    float*          stats2 = (float*)(ws + 1053184);            // 1,048,576
    unsigned short* wqkvT  = (unsigned short*)(ws + 2101760);   // 221,184
    unsigned short* wprojT = (unsigned short*)(ws + 2322944);   // 73,728
    unsigned short* w1T    = (unsigned short*)(ws + 2396672);   // 294,912
    unsigned short* w2T    = (unsigned short*)(ws + 2691584);   // 294,912
    float*          btab   = (float*)(ws + 2986496);            // 1,847,808
    unsigned short* qkvb_c = (unsigned short*)(ws + 4834304);   // [18620][576] bf16
    unsigned short* hq_c   = (unsigned short*)(ws + 4834304);   // [16384][768] bf16 (aliases)
    unsigned short* attn_c = (unsigned short*)(ws + 30000128);  // [18620][192] bf16
    float*          dout   = (float*)d_out;                     // fp32 out == x1 buffer

    mod_k<<<1, 256, 0, stream>>>(tvec, wa1, wa2, ba2, mod);
    prep_k<<<3533, 256, 0, stream>>>(w_qkv, w_proj, w1, w2, relb, wqkvT, wprojT, w1T, w2T, btab);
    stats_f32_k<<<32768, 256, 0, stream>>>(x, stats1);

    // qkv -> attention -> proj(+residual scatter into d_out as fp32 x1), 8 window-chunks
    for (int wc = 0; wc < 8; ++wc) {
        int r0 = wc * 18620;
        gemm_k<4, 1, 0><<<dim3(5, 146), 256, 0, stream>>>(
            nullptr, x, wqkvT, b_qkv, qkvb_c, nullptr, nullptr, stats1, mod, r0, 18620, 576, 192);
        attn_k<<<1140, 256, 0, stream>>>(qkvb_c, btab, attn_c, wc * 190);
        gemm_k<2, 0, 2><<<dim3(3, 146), 256, 0, stream>>>(
            attn_c, nullptr, wprojT, b_proj, nullptr, dout, x, nullptr, mod, r0, 18620, 192, 192);
    }

    stats_f32_k<<<32768, 256, 0, stream>>>(dout, stats2);

    // MLP: fc1(+LN2 fused staging, gelu) -> fc2(in-place final residual on d_out), 8 chunks
    for (int q = 0; q < 8; ++q) {
        int r0 = q * 16384;
        gemm_k<4, 2, 1><<<dim3(6, 128), 256, 0, stream>>>(
            nullptr, dout, w1T, b1, hq_c, nullptr, nullptr, stats2, mod, r0, 16384, 768, 192);
        gemm_k<2, 0, 3><<<dim3(3, 128), 256, 0, stream>>>(
            hq_c, nullptr, w2T, b2, nullptr, dout, nullptr, nullptr, mod, r0, 16384, 192, 768);
    }
}

// Round 7
// 1041.329 us; speedup vs baseline: 1.4020x; 1.3551x over previous
//
#include <hip/hip_runtime.h>
#include <hip/hip_bf16.h>

// ---------- types ----------
typedef __bf16 bf16x8 __attribute__((ext_vector_type(8)));
typedef float  f32x4  __attribute__((ext_vector_type(4)));
typedef unsigned int u32x4 __attribute__((ext_vector_type(4)));

__device__ inline unsigned short f2bf(float f) {
    union { __hip_bfloat16 h; unsigned short u; } cv;
    cv.h = __float2bfloat16(f);
    return cv.u;
}

// load 8 bf16 = two 8B halves at col +0 and col +16 (k-halves of 16x16x32)
__device__ inline bf16x8 load8(const unsigned short* p) {
    uint2 lo = *(const uint2*)(p);
    uint2 hi = *(const uint2*)(p + 16);
    u32x4 v; v[0] = lo.x; v[1] = lo.y; v[2] = hi.x; v[3] = hi.y;
    return __builtin_bit_cast(bf16x8, v);
}

__device__ inline f32x4 mfma16(bf16x8 a, bf16x8 b, f32x4 c) {
    return __builtin_amdgcn_mfma_f32_16x16x32_bf16(a, b, c, 0, 0, 0);
}

// window-row (global, 0..148959) -> spatial token (0..131071); false if pad
__device__ inline bool winmapT(int gg, int& T) {
    int win = gg / 98, n = gg % 98;
    int wdi = win / 190, rem = win % 190, whi = rem / 19, wwi = rem % 19;
    int td = n / 49, th = (n / 7) % 7, tw = n % 7;
    int sd = (wdi * 2 + td + 1) & 15;
    int sh = whi * 7 + th + 3; if (sh >= 70) sh -= 70;
    int sw = wwi * 7 + tw + 3; if (sw >= 133) sw -= 133;
    if (sh < 64 && sw < 128) { T = (sd * 64 + sh) * 128 + sw; return true; }
    return false;
}

// ---------- K0: mod = silu(t) @ wa1 @ wa2 + ba2  (1152 floats) ----------
__global__ __launch_bounds__(256) void mod_k(const float* __restrict__ t,
    const float* __restrict__ wa1, const float* __restrict__ wa2,
    const float* __restrict__ ba2, float* __restrict__ mod)
{
    __shared__ float st[192];
    __shared__ float a[24];
    int tid = threadIdx.x;
    if (tid < 192) { float x = t[tid]; st[tid] = x / (1.f + __expf(-x)); }
    __syncthreads();
    if (tid < 24) {
        float s = 0.f;
        for (int c = 0; c < 192; ++c) s += st[c] * wa1[c * 24 + tid];
        a[tid] = s;
    }
    __syncthreads();
    for (int j = tid; j < 1152; j += 256) {
        float s = ba2[j];
        for (int r = 0; r < 24; ++r) s += a[r] * wa2[r * 1152 + j];
        mod[j] = s;
    }
}

// ---------- K1: weight transposes (fp32 -> bf16, [N][K]) + fused bias+mask table ----------
// btab[(mt*6+h)*9604 + n*98 + m] = rel_bias(h,n,m) + mask(mt,n,m)
__global__ __launch_bounds__(256) void prep_k(
    const float* __restrict__ wqkv, const float* __restrict__ wproj,
    const float* __restrict__ w1, const float* __restrict__ w2,
    const float* __restrict__ relb,
    unsigned short* __restrict__ wqkvT, unsigned short* __restrict__ wprojT,
    unsigned short* __restrict__ w1T, unsigned short* __restrict__ w2T,
    float* __restrict__ btab)
{
    int i = blockIdx.x * 256 + threadIdx.x;
    if (i < 110592) { int n = i / 192, k = i % 192; wqkvT[i] = f2bf(wqkv[k * 576 + n]); return; }
    i -= 110592;
    if (i < 36864)  { int n = i / 192, k = i % 192; wprojT[i] = f2bf(wproj[k * 192 + n]); return; }
    i -= 36864;
    if (i < 147456) { int n = i / 192, k = i % 192; w1T[i] = f2bf(w1[k * 768 + n]); return; }
    i -= 147456;
    if (i < 147456) { int n = i / 768, k = i % 768; w2T[i] = f2bf(w2[k * 192 + n]); return; }
    i -= 147456;
    if (i < 461952) {
        int mt = i / 57624, rem = i % 57624;
        int h = rem / 9604, rm2 = rem % 9604;
        int n = rm2 / 98, m = rm2 % 98;
        int tdn = n / 49, thn = (n / 7) % 7, twn = n % 7;
        int tdm = m / 49, thm = (m / 7) % 7, twm = m % 7;
        int idx = (tdn - tdm + 1) * 169 + (thn - thm + 6) * 13 + (twn - twm + 6);
        float b = relb[idx * 6 + h];
        int bd = mt & 1, bh = (mt >> 1) & 1, bw = (mt >> 2) & 1;
        int idn = (bd ? (tdn == 0 ? 1 : 2) : 0) * 9 + (bh ? (thn < 4 ? 1 : 2) : 0) * 3 + (bw ? (twn < 4 ? 1 : 2) : 0);
        int idm = (bd ? (tdm == 0 ? 1 : 2) : 0) * 9 + (bh ? (thm < 4 ? 1 : 2) : 0) * 3 + (bw ? (twm < 4 ? 1 : 2) : 0);
        btab[i] = b + ((idn != idm) ? -100.f : 0.f);
    }
}

// ---------- stats: per-token LN mean/rstd over fp32 [tok][192] ----------
__global__ __launch_bounds__(256) void stats_f32_k(const float* __restrict__ x,
    float* __restrict__ st)
{
    int tok = blockIdx.x * 4 + (threadIdx.x >> 6);
    int lane = threadIdx.x & 63;
    const float* p = x + (size_t)tok * 192;
    float a = p[lane], b = p[64 + lane], c = p[128 + lane];
    float s = a + b + c, q = a * a + b * b + c * c;
    for (int m = 32; m; m >>= 1) { s += __shfl_xor(s, m); q += __shfl_xor(q, m); }
    if (lane == 0) {
        float mean = s * (1.f / 192.f);
        float var  = q * (1.f / 192.f) - mean * mean;
        st[2 * tok] = mean;
        st[2 * tok + 1] = rsqrtf(var + 1e-6f);
    }
}

// ---------- GEMM: C[M][N] = A[M][K](bf16) * BT[N][K]^T(bf16) + epilogue ----------
// 128 x (FN*32) tile, 4 waves 2x2; wave = 64 x FN*16 via 4 x FN frags of 16x16x32.
// STAGE: 0 = A plain bf16 [M][K]; 1 = virtual modulate(LN(x)) window gather;
//        2 = virtual modulate(LN(x1)) from fp32 x1
// EPI:   0 = bias->bf16; 1 = bias+gelu->bf16; 2 = proj scatter residual->fp32 out;
//        3 = fc2 in-place final residual on fp32 out
template<int FN, int STAGE, int EPI>
__global__ __launch_bounds__(256) void gemm_k(
    const unsigned short* __restrict__ A, const float* __restrict__ Af,
    const unsigned short* __restrict__ BT, const float* __restrict__ bias,
    unsigned short* __restrict__ outB, float* outF,
    const float* __restrict__ auxF, const float* __restrict__ stats,
    const float* __restrict__ mod, int row0, int M, int N, int K)
{
    constexpr int BN = FN * 32;
    __shared__ unsigned short As[128][44];
    __shared__ unsigned short Bs[BN][44];
    const int t = threadIdx.x;
    const int n0 = blockIdx.x * BN, m0 = blockIdx.y * 128;
    const int lr = t >> 2, lk = (t & 3) * 8;
    const int wid = t >> 6, lane = t & 63;
    const int lg = lane >> 4, l16 = lane & 15;
    const int wm = (wid >> 1) * 64, wn = (wid & 1) * (FN * 16);
    f32x4 acc[4][FN] = {};

    // per-row staging state for rows lr and lr+64
    float mn[2] = {0.f, 0.f}, rs[2] = {0.f, 0.f};
    size_t sbase[2] = {0, 0};
    bool va[2] = {false, false};
    #pragma unroll
    for (int rr = 0; rr < 2; ++rr) {
        int g = m0 + lr + rr * 64;
        if (STAGE == 1) {
            int T;
            if (g < M && winmapT(row0 + g, T)) {
                va[rr] = true; sbase[rr] = (size_t)T * 192;
                mn[rr] = stats[2 * T]; rs[rr] = stats[2 * T + 1];
            }
        } else if (STAGE == 2) {
            int tok = row0 + g;
            sbase[rr] = (size_t)tok * 192;
            mn[rr] = stats[2 * tok]; rs[rr] = stats[2 * tok + 1];
        }
    }

    for (int kk = 0; kk < K; kk += 32) {
        #pragma unroll
        for (int rr = 0; rr < 2; ++rr) {
            int r = lr + rr * 64;
            int g = m0 + r;
            uint4 w = make_uint4(0u, 0u, 0u, 0u);
            if (STAGE == 0) {
                if (g < M) w = *(const uint4*)(A + (size_t)g * K + kk + lk);
            } else if (STAGE == 1) {
                if (va[rr]) {
                    float4 xa = *(const float4*)(Af + sbase[rr] + kk + lk);
                    float4 xb = *(const float4*)(Af + sbase[rr] + kk + lk + 4);
                    float xs[8] = {xa.x, xa.y, xa.z, xa.w, xb.x, xb.y, xb.z, xb.w};
                    unsigned short o[8];
                    #pragma unroll
                    for (int j = 0; j < 8; ++j) {
                        int c = kk + lk + j;
                        o[j] = f2bf((xs[j] - mn[rr]) * rs[rr] * (1.f + mod[192 + c]) + mod[c]);
                    }
                    w = make_uint4((unsigned)o[0] | ((unsigned)o[1] << 16), (unsigned)o[2] | ((unsigned)o[3] << 16),
                                   (unsigned)o[4] | ((unsigned)o[5] << 16), (unsigned)o[6] | ((unsigned)o[7] << 16));
                }
            } else { // STAGE 2
                float4 xa = *(const float4*)(Af + sbase[rr] + kk + lk);
                float4 xb = *(const float4*)(Af + sbase[rr] + kk + lk + 4);
                float xs[8] = {xa.x, xa.y, xa.z, xa.w, xb.x, xb.y, xb.z, xb.w};
                unsigned short o[8];
                #pragma unroll
                for (int j = 0; j < 8; ++j) {
                    int c = kk + lk + j;
                    o[j] = f2bf((xs[j] - mn[rr]) * rs[rr] * (1.f + mod[768 + c]) + mod[576 + c]);
                }
                w = make_uint4((unsigned)o[0] | ((unsigned)o[1] << 16), (unsigned)o[2] | ((unsigned)o[3] << 16),
                               (unsigned)o[4] | ((unsigned)o[5] << 16), (unsigned)o[6] | ((unsigned)o[7] << 16));
            }
            *(uint2*)(&As[r][lk])     = make_uint2(w.x, w.y);
            *(uint2*)(&As[r][lk + 4]) = make_uint2(w.z, w.w);
        }
        #pragma unroll
        for (int rr = 0; rr < BN / 64; ++rr) {
            int r = lr + rr * 64;
            int gn = n0 + r;
            uint4 w = make_uint4(0u, 0u, 0u, 0u);
            if (gn < N) w = *(const uint4*)(BT + (size_t)gn * K + kk + lk);
            *(uint2*)(&Bs[r][lk])     = make_uint2(w.x, w.y);
            *(uint2*)(&Bs[r][lk + 4]) = make_uint2(w.z, w.w);
        }
        __syncthreads();
        bf16x8 af[4], bv[FN];
        #pragma unroll
        for (int i = 0; i < 4; ++i) af[i] = load8(&As[wm + i * 16 + l16][4 * lg]);
        #pragma unroll
        for (int j = 0; j < FN; ++j) bv[j] = load8(&Bs[wn + j * 16 + l16][4 * lg]);
        #pragma unroll
        for (int i = 0; i < 4; ++i)
        #pragma unroll
        for (int j = 0; j < FN; ++j)
            acc[i][j] = mfma16(af[i], bv[j], acc[i][j]);
        __syncthreads();
    }

    #pragma unroll
    for (int i = 0; i < 4; ++i)
    #pragma unroll
    for (int j = 0; j < FN; ++j) {
        int gcol = n0 + wn + j * 16 + l16;
        if (gcol >= N) continue;
        float b = bias[gcol];
        #pragma unroll
        for (int e = 0; e < 4; ++e) {
            int grow = m0 + wm + i * 16 + lg * 4 + e;
            if (grow >= M) continue;
            float v = acc[i][j][e] + b;
            if (EPI == 0) {
                outB[(size_t)grow * N + gcol] = f2bf(v);
            } else if (EPI == 1) {
                float gl = 0.5f * v * (1.f + erff(v * 0.70710678118654752f));
                outB[(size_t)grow * N + gcol] = f2bf(gl);
            } else if (EPI == 2) {
                int T;
                if (winmapT(row0 + grow, T)) {
                    size_t idx = (size_t)T * 192 + gcol;
                    outF[idx] = auxF[idx] + mod[384 + gcol] * v;
                }
            } else {
                size_t idx = (size_t)(row0 + grow) * 192 + gcol;
                outF[idx] = outF[idx] + mod[960 + gcol] * v;
            }
        }
    }
}

// ---------- attention: one block per (window, head), in-register softmax ----------
// btab is the fused (rel_bias + mask) table: 48 x 9604 fp32, L2-resident.
__global__ __launch_bounds__(256) void attn_k(
    const unsigned short* __restrict__ qkv, const float* __restrict__ btab,
    unsigned short* __restrict__ out)
{
    __shared__ __align__(16) char smem[40320];
    unsigned short* Qs  = (unsigned short*)smem;            // [112][44]  (phase 1-2)
    unsigned short* Ks  = (unsigned short*)(smem + 9856);   // [112][44]  (phase 1-2)
    unsigned short* Pbf = (unsigned short*)smem;            // [112][140] (phase 3-4, aliases Qs/Ks)
    unsigned short* VT  = (unsigned short*)(smem + 31360);  // [32][140]

    const int blk = blockIdx.x;
    const int win = blk / 6, h = blk % 6;   // global window id
    const int t = threadIdx.x;
    const int wid = t >> 6, lg = (t >> 4) & 3, l16 = t & 15;
    const size_t rb = (size_t)win * 98;

    // fused bias+mask row base for this (window-type, head)
    const int wdi = win / 190, remw = win % 190, whi = remw / 19, wwi = remw % 19;
    const int mt = (wdi == 7 ? 1 : 0) | (whi == 9 ? 2 : 0) | (wwi == 18 ? 4 : 0);
    const float* bt = btab + (size_t)(mt * 6 + h) * 9604;

    // ---- phase 1: stage Q,K rows ([98][32] + zero pad rows) and V^T ----
    for (int i = t; i < 98 * 4; i += 256) {
        int r = i >> 2, cg = (i & 3) * 8;
        uint4 q = *(const uint4*)(qkv + (rb + r) * 576 + h * 32 + cg);
        uint4 k = *(const uint4*)(qkv + (rb + r) * 576 + 192 + h * 32 + cg);
        *(uint2*)(Qs + r * 44 + cg)     = make_uint2(q.x, q.y);
        *(uint2*)(Qs + r * 44 + cg + 4) = make_uint2(q.z, q.w);
        *(uint2*)(Ks + r * 44 + cg)     = make_uint2(k.x, k.y);
        *(uint2*)(Ks + r * 44 + cg + 4) = make_uint2(k.z, k.w);
    }
    for (int i = t; i < 14 * 32; i += 256) {
        int r = 98 + (i >> 5), c = i & 31;
        Qs[r * 44 + c] = 0; Ks[r * 44 + c] = 0;
    }
    for (int i = t; i < 32 * 42; i += 256) { int c = i / 42, m = 98 + i % 42; VT[c * 140 + m] = 0; }
    for (int i = t; i < 98 * 32; i += 256) {
        int m = i >> 5, c = i & 31;
        VT[c * 140 + m] = qkv[(rb + m) * 576 + 384 + h * 32 + c];
    }
    __syncthreads();

    // ---- phase 2: S = Q K^T, fragments stay in registers ----
    f32x4 acc[2][7];
    {
        bf16x8 kb[7];
        #pragma unroll
        for (int fn = 0; fn < 7; ++fn) kb[fn] = load8(Ks + (fn * 16 + l16) * 44 + 4 * lg);
        #pragma unroll
        for (int fi = 0; fi < 2; ++fi) {
            int fm = wid + fi * 4;
            if (fm < 7) {
                bf16x8 qa = load8(Qs + (fm * 16 + l16) * 44 + 4 * lg);
                #pragma unroll
                for (int fn = 0; fn < 7; ++fn) {
                    f32x4 z = {};
                    acc[fi][fn] = mfma16(qa, kb[fn], z);
                }
            }
        }
    }
    __syncthreads();   // Qs/Ks dead; Pbf region may now be written

    // ---- phase 3: in-register softmax (scale + fused bias/mask, 16-lane row reduce) ----
    const float SCALE = 0.17677669529663687f;
    float rinv[2][4];
    #pragma unroll
    for (int fi = 0; fi < 2; ++fi) {
        int fm = wid + fi * 4;
        if (fm < 7) {
            #pragma unroll
            for (int e = 0; e < 4; ++e) {
                int r = fm * 16 + lg * 4 + e;
                float mx = -1e30f;
                #pragma unroll
                for (int fn = 0; fn < 7; ++fn) {
                    int c = fn * 16 + l16;
                    float s = -1e30f;
                    if (r < 98 && c < 98) s = fmaf(acc[fi][fn][e], SCALE, bt[r * 98 + c]);
                    acc[fi][fn][e] = s;
                    mx = fmaxf(mx, s);
                }
                #pragma unroll
                for (int m = 1; m < 16; m <<= 1) mx = fmaxf(mx, __shfl_xor(mx, m));
                float sum = 0.f;
                #pragma unroll
                for (int fn = 0; fn < 7; ++fn) {
                    float p = __expf(acc[fi][fn][e] - mx);
                    acc[fi][fn][e] = p;
                    sum += p;
                }
                #pragma unroll
                for (int m = 1; m < 16; m <<= 1) sum += __shfl_xor(sum, m);
                rinv[fi][e] = 1.f / sum;
            }
            #pragma unroll
            for (int fn = 0; fn < 7; ++fn) {
                int c = fn * 16 + l16;
                #pragma unroll
                for (int e = 0; e < 4; ++e) {
                    int r = fm * 16 + lg * 4 + e;
                    float val = (r < 98 && c < 98) ? acc[fi][fn][e] : 0.f;
                    Pbf[r * 140 + c] = f2bf(val);
                }
            }
        }
    }
    // zero P cols 112..127 (never covered by fragment writes)
    for (int i = t; i < 112 * 8; i += 256) {
        int r = i >> 3, c = 112 + (i & 7) * 2;
        *(unsigned int*)(Pbf + r * 140 + c) = 0u;
    }
    __syncthreads();

    // ---- phase 4: O = P V (K padded to 128), divide by in-register row sums ----
    #pragma unroll
    for (int fi = 0; fi < 2; ++fi) {
        int fm = wid + fi * 4;
        if (fm < 7) {
            bf16x8 sa[4];
            #pragma unroll
            for (int ks = 0; ks < 4; ++ks)
                sa[ks] = load8(Pbf + (fm * 16 + l16) * 140 + ks * 32 + 4 * lg);
            #pragma unroll
            for (int fn = 0; fn < 2; ++fn) {
                f32x4 o = {};
                #pragma unroll
                for (int ks = 0; ks < 4; ++ks) {
                    bf16x8 vb = load8(VT + (fn * 16 + l16) * 140 + ks * 32 + 4 * lg);
                    o = mfma16(sa[ks], vb, o);
                }
                #pragma unroll
                for (int e = 0; e < 4; ++e) {
                    int r = fm * 16 + lg * 4 + e;
                    if (r < 98) {
                        out[(rb + r) * 192 + h * 32 + fn * 16 + l16] = f2bf(o[e] * rinv[fi][e]);
                    }
                }
            }
        }
    }
}

// ---------- launch ----------
// ws_size = 384 MiB (measured via harness poison fill). Un-chunked pipeline, 9 launches.
// d_out (fp32 [131072][192]) is ALSO the x1 buffer.
// layout: fixed tables to 4,834,304; qkvb @4,834,304 (171.6MB) -> attn_c @176,436,224 (57.2MB);
//         h (201.3MB) aliases qkvb+attn_c region after proj. span ~234MB < 402MB.
extern "C" void kernel_launch(void* const* d_in, const int* in_sizes, int n_in,
                              void* d_out, int out_size, void* d_ws, size_t ws_size,
                              hipStream_t stream)
{
    const float* x      = (const float*)d_in[0];
    const float* tvec   = (const float*)d_in[2];
    const float* w_qkv  = (const float*)d_in[3];
    const float* b_qkv  = (const float*)d_in[4];
    const float* relb   = (const float*)d_in[5];
    const float* w_proj = (const float*)d_in[6];
    const float* b_proj = (const float*)d_in[7];
    const float* w1     = (const float*)d_in[8];
    const float* b1     = (const float*)d_in[9];
    const float* w2     = (const float*)d_in[10];
    const float* b2     = (const float*)d_in[11];
    const float* wa1    = (const float*)d_in[12];
    const float* wa2    = (const float*)d_in[13];
    const float* ba2    = (const float*)d_in[14];

    char* ws = (char*)d_ws;
    float*          mod    = (float*)ws;                        // 4,608
    float*          stats1 = (float*)(ws + 4608);               // 1,048,576
    float*          stats2 = (float*)(ws + 1053184);            // 1,048,576
    unsigned short* wqkvT  = (unsigned short*)(ws + 2101760);   // 221,184
    unsigned short* wprojT = (unsigned short*)(ws + 2322944);   // 73,728
    unsigned short* w1T    = (unsigned short*)(ws + 2396672);   // 294,912
    unsigned short* w2T    = (unsigned short*)(ws + 2691584);   // 294,912
    float*          btab   = (float*)(ws + 2986496);            // 1,847,808
    unsigned short* qkvb   = (unsigned short*)(ws + 4834304);   // [148960][576] bf16, 171.6MB
    unsigned short* h      = (unsigned short*)(ws + 4834304);   // [131072][768] bf16 (aliases, after proj)
    unsigned short* attn_c = (unsigned short*)(ws + 176436224); // [148960][192] bf16, 57.2MB
    float*          dout   = (float*)d_out;                     // fp32 out == x1 buffer

    mod_k<<<1, 256, 0, stream>>>(tvec, wa1, wa2, ba2, mod);
    prep_k<<<3533, 256, 0, stream>>>(w_qkv, w_proj, w1, w2, relb, wqkvT, wprojT, w1T, w2T, btab);
    stats_f32_k<<<32768, 256, 0, stream>>>(x, stats1);

    // full qkv GEMM: [148960][576]
    gemm_k<4, 1, 0><<<dim3(5, 1164), 256, 0, stream>>>(
        nullptr, x, wqkvT, b_qkv, qkvb, nullptr, nullptr, stats1, mod, 0, 148960, 576, 192);
    // full attention: 1520 windows x 6 heads
    attn_k<<<9120, 256, 0, stream>>>(qkvb, btab, attn_c);
    // full proj + residual scatter -> fp32 x1 (in d_out)
    gemm_k<2, 0, 2><<<dim3(3, 1164), 256, 0, stream>>>(
        attn_c, nullptr, wprojT, b_proj, nullptr, dout, x, nullptr, mod, 0, 148960, 192, 192);

    stats_f32_k<<<32768, 256, 0, stream>>>(dout, stats2);

    // full fc1 (+LN2 fused staging, gelu) -> h
    gemm_k<4, 2, 1><<<dim3(6, 1024), 256, 0, stream>>>(
        nullptr, dout, w1T, b1, h, nullptr, nullptr, stats2, mod, 0, 131072, 768, 192);
    // full fc2 (in-place final residual on d_out)
    gemm_k<2, 0, 3><<<dim3(3, 1024), 256, 0, stream>>>(
        h, nullptr, w2T, b2, nullptr, dout, nullptr, nullptr, mod, 0, 131072, 192, 768);
}

// Round 8
// 1020.349 us; speedup vs baseline: 1.4308x; 1.0206x over previous
//
#include <hip/hip_runtime.h>
#include <hip/hip_bf16.h>

// ---------- types ----------
typedef __bf16 bf16x8 __attribute__((ext_vector_type(8)));
typedef float  f32x4  __attribute__((ext_vector_type(4)));
typedef unsigned int u32x4 __attribute__((ext_vector_type(4)));

__device__ inline unsigned short f2bf(float f) {
    union { __hip_bfloat16 h; unsigned short u; } cv;
    cv.h = __float2bfloat16(f);
    return cv.u;
}
__device__ inline float bf2f(unsigned short u) {
    union { unsigned int i; float f; } c; c.i = ((unsigned int)u) << 16; return c.f;
}

// load 8 bf16 = two 8B halves at col +0 and col +16 (k-halves of 16x16x32)
__device__ inline bf16x8 load8(const unsigned short* p) {
    uint2 lo = *(const uint2*)(p);
    uint2 hi = *(const uint2*)(p + 16);
    u32x4 v; v[0] = lo.x; v[1] = lo.y; v[2] = hi.x; v[3] = hi.y;
    return __builtin_bit_cast(bf16x8, v);
}

__device__ inline f32x4 mfma16(bf16x8 a, bf16x8 b, f32x4 c) {
    return __builtin_amdgcn_mfma_f32_16x16x32_bf16(a, b, c, 0, 0, 0);
}

// window-row (global, 0..148959) -> spatial token (0..131071); false if pad
__device__ inline bool winmapT(int gg, int& T) {
    int win = gg / 98, n = gg % 98;
    int wdi = win / 190, rem = win % 190, whi = rem / 19, wwi = rem % 19;
    int td = n / 49, th = (n / 7) % 7, tw = n % 7;
    int sd = (wdi * 2 + td + 1) & 15;
    int sh = whi * 7 + th + 3; if (sh >= 70) sh -= 70;
    int sw = wwi * 7 + tw + 3; if (sw >= 133) sw -= 133;
    if (sh < 64 && sw < 128) { T = (sd * 64 + sh) * 128 + sw; return true; }
    return false;
}

// ---------- K0: mod = silu(t) @ wa1 @ wa2 + ba2  (1152 floats) ----------
__global__ __launch_bounds__(256) void mod_k(const float* __restrict__ t,
    const float* __restrict__ wa1, const float* __restrict__ wa2,
    const float* __restrict__ ba2, float* __restrict__ mod)
{
    __shared__ float st[192];
    __shared__ float a[24];
    int tid = threadIdx.x;
    if (tid < 192) { float x = t[tid]; st[tid] = x / (1.f + __expf(-x)); }
    __syncthreads();
    if (tid < 24) {
        float s = 0.f;
        for (int c = 0; c < 192; ++c) s += st[c] * wa1[c * 24 + tid];
        a[tid] = s;
    }
    __syncthreads();
    for (int j = tid; j < 1152; j += 256) {
        float s = ba2[j];
        for (int r = 0; r < 24; ++r) s += a[r] * wa2[r * 1152 + j];
        mod[j] = s;
    }
}

// ---------- K1: weight transposes (fp32 -> bf16, [N][K]) + fragment-ordered bias table ----------
// btabF layout (bf16): [mt 8][h 6][fm 7][le 16][l16 16][fn 8]; value for (r=fm*16+le, c=fn*16+l16)
//   = rel_bias(h,r,c) + mask(mt,r,c), or -1e30 when fn==7 | r>=98 | c>=98 (bakes pad masking).
__global__ __launch_bounds__(256) void prep_k(
    const float* __restrict__ wqkv, const float* __restrict__ wproj,
    const float* __restrict__ w1, const float* __restrict__ w2,
    const float* __restrict__ relb,
    unsigned short* __restrict__ wqkvT, unsigned short* __restrict__ wprojT,
    unsigned short* __restrict__ w1T, unsigned short* __restrict__ w2T,
    unsigned short* __restrict__ btabF)
{
    int i = blockIdx.x * 256 + threadIdx.x;
    if (i < 110592) { int n = i / 192, k = i % 192; wqkvT[i] = f2bf(wqkv[k * 576 + n]); return; }
    i -= 110592;
    if (i < 36864)  { int n = i / 192, k = i % 192; wprojT[i] = f2bf(wproj[k * 192 + n]); return; }
    i -= 36864;
    if (i < 147456) { int n = i / 192, k = i % 192; w1T[i] = f2bf(w1[k * 768 + n]); return; }
    i -= 147456;
    if (i < 147456) { int n = i / 768, k = i % 768; w2T[i] = f2bf(w2[k * 192 + n]); return; }
    i -= 147456;
    if (i < 688128) {
        int mt = i / 86016, r1 = i % 86016;
        int h  = r1 / 14336, r2 = r1 % 14336;
        int fm = r2 / 2048,  r3 = r2 % 2048;
        int le = r3 / 128,   r4 = r3 % 128;
        int l16 = r4 / 8,    fn = r4 % 8;
        int r = fm * 16 + le, c = fn * 16 + l16;
        float val;
        if (fn == 7 || r >= 98 || c >= 98) {
            val = -1e30f;
        } else {
            int tdn = r / 49, thn = (r / 7) % 7, twn = r % 7;
            int tdm = c / 49, thm = (c / 7) % 7, twm = c % 7;
            int idx = (tdn - tdm + 1) * 169 + (thn - thm + 6) * 13 + (twn - twm + 6);
            float b = relb[idx * 6 + h];
            int bd = mt & 1, bh = (mt >> 1) & 1, bw = (mt >> 2) & 1;
            int idn = (bd ? (tdn == 0 ? 1 : 2) : 0) * 9 + (bh ? (thn < 4 ? 1 : 2) : 0) * 3 + (bw ? (twn < 4 ? 1 : 2) : 0);
            int idm = (bd ? (tdm == 0 ? 1 : 2) : 0) * 9 + (bh ? (thm < 4 ? 1 : 2) : 0) * 3 + (bw ? (twm < 4 ? 1 : 2) : 0);
            val = b + ((idn != idm) ? -100.f : 0.f);
        }
        btabF[i] = f2bf(val);
    }
}

// ---------- stats: per-token LN mean/rstd over fp32 [tok][192] ----------
__global__ __launch_bounds__(256) void stats_f32_k(const float* __restrict__ x,
    float* __restrict__ st)
{
    int tok = blockIdx.x * 4 + (threadIdx.x >> 6);
    int lane = threadIdx.x & 63;
    const float* p = x + (size_t)tok * 192;
    float a = p[lane], b = p[64 + lane], c = p[128 + lane];
    float s = a + b + c, q = a * a + b * b + c * c;
    for (int m = 32; m; m >>= 1) { s += __shfl_xor(s, m); q += __shfl_xor(q, m); }
    if (lane == 0) {
        float mean = s * (1.f / 192.f);
        float var  = q * (1.f / 192.f) - mean * mean;
        st[2 * tok] = mean;
        st[2 * tok + 1] = rsqrtf(var + 1e-6f);
    }
}

// ---------- GEMM: C[M][N] = A[M][K](bf16) * BT[N][K]^T(bf16) + epilogue ----------
// 128 x (FN*32) tile, 4 waves 2x2; wave = 64 x FN*16 via 4 x FN frags of 16x16x32.
// STAGE: 0 = A plain bf16 [M][K]; 1 = virtual modulate(LN(x)) window gather;
//        2 = virtual modulate(LN(x1)) from fp32 x1
// EPI:   0 = bias->bf16; 1 = bias+gelu->bf16; 2 = proj scatter residual->fp32 out;
//        3 = fc2 in-place final residual on fp32 out
template<int FN, int STAGE, int EPI>
__global__ __launch_bounds__(256) void gemm_k(
    const unsigned short* __restrict__ A, const float* __restrict__ Af,
    const unsigned short* __restrict__ BT, const float* __restrict__ bias,
    unsigned short* __restrict__ outB, float* outF,
    const float* __restrict__ auxF, const float* __restrict__ stats,
    const float* __restrict__ mod, int row0, int M, int N, int K)
{
    constexpr int BN = FN * 32;
    __shared__ unsigned short As[128][44];
    __shared__ unsigned short Bs[BN][44];
    const int t = threadIdx.x;
    const int n0 = blockIdx.x * BN, m0 = blockIdx.y * 128;
    const int lr = t >> 2, lk = (t & 3) * 8;
    const int wid = t >> 6, lane = t & 63;
    const int lg = lane >> 4, l16 = lane & 15;
    const int wm = (wid >> 1) * 64, wn = (wid & 1) * (FN * 16);
    f32x4 acc[4][FN] = {};

    // per-row staging state for rows lr and lr+64
    float mn[2] = {0.f, 0.f}, rs[2] = {0.f, 0.f};
    size_t sbase[2] = {0, 0};
    bool va[2] = {false, false};
    #pragma unroll
    for (int rr = 0; rr < 2; ++rr) {
        int g = m0 + lr + rr * 64;
        if (STAGE == 1) {
            int T;
            if (g < M && winmapT(row0 + g, T)) {
                va[rr] = true; sbase[rr] = (size_t)T * 192;
                mn[rr] = stats[2 * T]; rs[rr] = stats[2 * T + 1];
            }
        } else if (STAGE == 2) {
            int tok = row0 + g;
            sbase[rr] = (size_t)tok * 192;
            mn[rr] = stats[2 * tok]; rs[rr] = stats[2 * tok + 1];
        }
    }

    for (int kk = 0; kk < K; kk += 32) {
        #pragma unroll
        for (int rr = 0; rr < 2; ++rr) {
            int r = lr + rr * 64;
            int g = m0 + r;
            uint4 w = make_uint4(0u, 0u, 0u, 0u);
            if (STAGE == 0) {
                if (g < M) w = *(const uint4*)(A + (size_t)g * K + kk + lk);
            } else if (STAGE == 1) {
                if (va[rr]) {
                    float4 xa = *(const float4*)(Af + sbase[rr] + kk + lk);
                    float4 xb = *(const float4*)(Af + sbase[rr] + kk + lk + 4);
                    float xs[8] = {xa.x, xa.y, xa.z, xa.w, xb.x, xb.y, xb.z, xb.w};
                    unsigned short o[8];
                    #pragma unroll
                    for (int j = 0; j < 8; ++j) {
                        int c = kk + lk + j;
                        o[j] = f2bf((xs[j] - mn[rr]) * rs[rr] * (1.f + mod[192 + c]) + mod[c]);
                    }
                    w = make_uint4((unsigned)o[0] | ((unsigned)o[1] << 16), (unsigned)o[2] | ((unsigned)o[3] << 16),
                                   (unsigned)o[4] | ((unsigned)o[5] << 16), (unsigned)o[6] | ((unsigned)o[7] << 16));
                }
            } else { // STAGE 2
                float4 xa = *(const float4*)(Af + sbase[rr] + kk + lk);
                float4 xb = *(const float4*)(Af + sbase[rr] + kk + lk + 4);
                float xs[8] = {xa.x, xa.y, xa.z, xa.w, xb.x, xb.y, xb.z, xb.w};
                unsigned short o[8];
                #pragma unroll
                for (int j = 0; j < 8; ++j) {
                    int c = kk + lk + j;
                    o[j] = f2bf((xs[j] - mn[rr]) * rs[rr] * (1.f + mod[768 + c]) + mod[576 + c]);
                }
                w = make_uint4((unsigned)o[0] | ((unsigned)o[1] << 16), (unsigned)o[2] | ((unsigned)o[3] << 16),
                               (unsigned)o[4] | ((unsigned)o[5] << 16), (unsigned)o[6] | ((unsigned)o[7] << 16));
            }
            *(uint2*)(&As[r][lk])     = make_uint2(w.x, w.y);
            *(uint2*)(&As[r][lk + 4]) = make_uint2(w.z, w.w);
        }
        #pragma unroll
        for (int rr = 0; rr < BN / 64; ++rr) {
            int r = lr + rr * 64;
            int gn = n0 + r;
            uint4 w = make_uint4(0u, 0u, 0u, 0u);
            if (gn < N) w = *(const uint4*)(BT + (size_t)gn * K + kk + lk);
            *(uint2*)(&Bs[r][lk])     = make_uint2(w.x, w.y);
            *(uint2*)(&Bs[r][lk + 4]) = make_uint2(w.z, w.w);
        }
        __syncthreads();
        bf16x8 af[4], bv[FN];
        #pragma unroll
        for (int i = 0; i < 4; ++i) af[i] = load8(&As[wm + i * 16 + l16][4 * lg]);
        #pragma unroll
        for (int j = 0; j < FN; ++j) bv[j] = load8(&Bs[wn + j * 16 + l16][4 * lg]);
        #pragma unroll
        for (int i = 0; i < 4; ++i)
        #pragma unroll
        for (int j = 0; j < FN; ++j)
            acc[i][j] = mfma16(af[i], bv[j], acc[i][j]);
        __syncthreads();
    }

    #pragma unroll
    for (int i = 0; i < 4; ++i)
    #pragma unroll
    for (int j = 0; j < FN; ++j) {
        int gcol = n0 + wn + j * 16 + l16;
        if (gcol >= N) continue;
        float b = bias[gcol];
        #pragma unroll
        for (int e = 0; e < 4; ++e) {
            int grow = m0 + wm + i * 16 + lg * 4 + e;
            if (grow >= M) continue;
            float v = acc[i][j][e] + b;
            if (EPI == 0) {
                outB[(size_t)grow * N + gcol] = f2bf(v);
            } else if (EPI == 1) {
                float gl = 0.5f * v * (1.f + erff(v * 0.70710678118654752f));
                outB[(size_t)grow * N + gcol] = f2bf(gl);
            } else if (EPI == 2) {
                int T;
                if (winmapT(row0 + grow, T)) {
                    size_t idx = (size_t)T * 192 + gcol;
                    outF[idx] = auxF[idx] + mod[384 + gcol] * v;
                }
            } else {
                size_t idx = (size_t)(row0 + grow) * 192 + gcol;
                outF[idx] = outF[idx] + mod[960 + gcol] * v;
            }
        }
    }
}

// ---------- attention: one block per (window, head) ----------
// Register-prefetched bias table (fragment-ordered bf16, masks baked as -1e30),
// async V staging (loads issued phase 1, LDS writes after QK^T), branch-free softmax.
__global__ __launch_bounds__(256) void attn_k(
    const unsigned short* __restrict__ qkv, const unsigned short* __restrict__ btabF,
    unsigned short* __restrict__ out)
{
    __shared__ __align__(16) char smem[40896];
    unsigned short* Qs  = (unsigned short*)smem;            // [112][44]  (phase 1-2)
    unsigned short* Ks  = (unsigned short*)(smem + 9856);   // [112][44]  (phase 1-2)
    unsigned short* Pbf = (unsigned short*)smem;            // [112][142] (phase 3-4, aliases Qs/Ks)
    unsigned short* VT  = (unsigned short*)(smem + 31808);  // [32][142]

    const int blk = blockIdx.x;
    const int win = blk / 6, h = blk % 6;
    const int t = threadIdx.x;
    const int wid = t >> 6, lg = (t >> 4) & 3, l16 = t & 15;
    const size_t rb = (size_t)win * 98;

    const int wdi = win / 190, remw = win % 190, whi = remw / 19, wwi = remw % 19;
    const int mt = (wdi == 7 ? 1 : 0) | (whi == 9 ? 2 : 0) | (wwi == 18 ? 4 : 0);
    const unsigned short* btF = btabF + (size_t)(mt * 6 + h) * 14336;

    // ---- phase 1: issue V loads to regs; stage Q,K to LDS (+ zero pad rows) ----
    uint4 vreg[2];
    const int vi0 = t, vi1 = t + 256;   // i = m*4 + g, valid < 392
    if (vi0 < 392) vreg[0] = *(const uint4*)(qkv + (rb + (vi0 >> 2)) * 576 + 384 + h * 32 + (vi0 & 3) * 8);
    if (vi1 < 392) vreg[1] = *(const uint4*)(qkv + (rb + (vi1 >> 2)) * 576 + 384 + h * 32 + (vi1 & 3) * 8);

    for (int i = t; i < 98 * 4; i += 256) {
        int r = i >> 2, cg = (i & 3) * 8;
        uint4 q = *(const uint4*)(qkv + (rb + r) * 576 + h * 32 + cg);
        uint4 k = *(const uint4*)(qkv + (rb + r) * 576 + 192 + h * 32 + cg);
        *(uint2*)(Qs + r * 44 + cg)     = make_uint2(q.x, q.y);
        *(uint2*)(Qs + r * 44 + cg + 4) = make_uint2(q.z, q.w);
        *(uint2*)(Ks + r * 44 + cg)     = make_uint2(k.x, k.y);
        *(uint2*)(Ks + r * 44 + cg + 4) = make_uint2(k.z, k.w);
    }
    for (int i = t; i < 14 * 32; i += 256) {
        int r = 98 + (i >> 5), c = i & 31;
        Qs[r * 44 + c] = 0; Ks[r * 44 + c] = 0;
    }
    __syncthreads();

    // ---- phase 2: S = Q K^T, fragments stay in registers ----
    f32x4 acc[2][7];
    {
        bf16x8 kb[7];
        #pragma unroll
        for (int fn = 0; fn < 7; ++fn) kb[fn] = load8(Ks + (fn * 16 + l16) * 44 + 4 * lg);
        #pragma unroll
        for (int fi = 0; fi < 2; ++fi) {
            int fm = wid + fi * 4;
            if (fm < 7) {
                bf16x8 qa = load8(Qs + (fm * 16 + l16) * 44 + 4 * lg);
                #pragma unroll
                for (int fn = 0; fn < 7; ++fn) {
                    f32x4 z = {};
                    acc[fi][fn] = mfma16(qa, kb[fn], z);
                }
            }
        }
    }
    __syncthreads();   // Qs/Ks dead; Pbf/VT region may now be written

    // ---- phase 2.5: issue bias-frag loads; write V^T from regs; zero pads ----
    uint4 btreg[2][4];
    #pragma unroll
    for (int fi = 0; fi < 2; ++fi) {
        int fm = wid + fi * 4;
        int fmc = (fm < 7) ? fm : 0;
        #pragma unroll
        for (int e = 0; e < 4; ++e)
            btreg[fi][e] = *(const uint4*)(btF + fmc * 2048 + (lg * 4 + e) * 128 + l16 * 8);
    }
    {
        if (vi0 < 392) {
            int m = vi0 >> 2, c0 = (vi0 & 3) * 8;
            const unsigned short* vp = (const unsigned short*)&vreg[0];
            #pragma unroll
            for (int j = 0; j < 8; ++j) VT[(c0 + j) * 142 + m] = vp[j];
        }
        if (vi1 < 392) {
            int m = vi1 >> 2, c0 = (vi1 & 3) * 8;
            const unsigned short* vp = (const unsigned short*)&vreg[1];
            #pragma unroll
            for (int j = 0; j < 8; ++j) VT[(c0 + j) * 142 + m] = vp[j];
        }
    }
    for (int i = t; i < 32 * 30; i += 256) { int c = i / 30, m = 98 + i % 30; VT[c * 142 + m] = 0; }
    for (int i = t; i < 112 * 8; i += 256) {
        int r = i >> 3, cc = 112 + (i & 7) * 2;
        *(unsigned int*)(Pbf + r * 142 + cc) = 0u;
    }

    // ---- phase 3: branch-free in-register softmax (bias/mask from btreg) ----
    const float SCALE = 0.17677669529663687f;
    float rinv[2][4];
    #pragma unroll
    for (int fi = 0; fi < 2; ++fi) {
        int fm = wid + fi * 4;
        if (fm < 7) {
            #pragma unroll
            for (int e = 0; e < 4; ++e) {
                const unsigned int bw[4] = {btreg[fi][e].x, btreg[fi][e].y, btreg[fi][e].z, btreg[fi][e].w};
                float mx = -1e30f;
                #pragma unroll
                for (int fn = 0; fn < 7; ++fn) {
                    unsigned short bu = (unsigned short)(bw[fn >> 1] >> ((fn & 1) * 16));
                    float s = fmaf(acc[fi][fn][e], SCALE, bf2f(bu));
                    acc[fi][fn][e] = s;
                    mx = fmaxf(mx, s);
                }
                #pragma unroll
                for (int m = 1; m < 16; m <<= 1) mx = fmaxf(mx, __shfl_xor(mx, m));
                float sum = 0.f;
                #pragma unroll
                for (int fn = 0; fn < 7; ++fn) {
                    float p = __expf(acc[fi][fn][e] - mx);
                    acc[fi][fn][e] = p;
                    sum += p;
                }
                #pragma unroll
                for (int m = 1; m < 16; m <<= 1) sum += __shfl_xor(sum, m);
                rinv[fi][e] = 1.f / sum;
            }
            #pragma unroll
            for (int fn = 0; fn < 7; ++fn) {
                int c = fn * 16 + l16;
                #pragma unroll
                for (int e = 0; e < 4; ++e) {
                    int r = fm * 16 + lg * 4 + e;
                    Pbf[r * 142 + c] = f2bf(acc[fi][fn][e]);
                }
            }
        }
    }
    __syncthreads();

    // ---- phase 4: O = P V (K padded to 128), divide by in-register row sums ----
    #pragma unroll
    for (int fi = 0; fi < 2; ++fi) {
        int fm = wid + fi * 4;
        if (fm < 7) {
            bf16x8 sa[4];
            #pragma unroll
            for (int ks = 0; ks < 4; ++ks)
                sa[ks] = load8(Pbf + (fm * 16 + l16) * 142 + ks * 32 + 4 * lg);
            #pragma unroll
            for (int fn = 0; fn < 2; ++fn) {
                f32x4 o = {};
                #pragma unroll
                for (int ks = 0; ks < 4; ++ks) {
                    bf16x8 vb = load8(VT + (fn * 16 + l16) * 142 + ks * 32 + 4 * lg);
                    o = mfma16(sa[ks], vb, o);
                }
                #pragma unroll
                for (int e = 0; e < 4; ++e) {
                    int r = fm * 16 + lg * 4 + e;
                    if (r < 98) {
                        out[(rb + r) * 192 + h * 32 + fn * 16 + l16] = f2bf(o[e] * rinv[fi][e]);
                    }
                }
            }
        }
    }
}

// ---------- launch ----------
// ws_size = 384 MiB. Un-chunked pipeline, 9 launches. d_out (fp32) is ALSO the x1 buffer.
extern "C" void kernel_launch(void* const* d_in, const int* in_sizes, int n_in,
                              void* d_out, int out_size, void* d_ws, size_t ws_size,
                              hipStream_t stream)
{
    const float* x      = (const float*)d_in[0];
    const float* tvec   = (const float*)d_in[2];
    const float* w_qkv  = (const float*)d_in[3];
    const float* b_qkv  = (const float*)d_in[4];
    const float* relb   = (const float*)d_in[5];
    const float* w_proj = (const float*)d_in[6];
    const float* b_proj = (const float*)d_in[7];
    const float* w1     = (const float*)d_in[8];
    const float* b1     = (const float*)d_in[9];
    const float* w2     = (const float*)d_in[10];
    const float* b2     = (const float*)d_in[11];
    const float* wa1    = (const float*)d_in[12];
    const float* wa2    = (const float*)d_in[13];
    const float* ba2    = (const float*)d_in[14];

    char* ws = (char*)d_ws;
    float*          mod    = (float*)ws;                        // 4,608
    float*          stats1 = (float*)(ws + 4608);               // 1,048,576
    float*          stats2 = (float*)(ws + 1053184);            // 1,048,576
    unsigned short* wqkvT  = (unsigned short*)(ws + 2101760);   // 221,184
    unsigned short* wprojT = (unsigned short*)(ws + 2322944);   // 73,728
    unsigned short* w1T    = (unsigned short*)(ws + 2396672);   // 294,912
    unsigned short* w2T    = (unsigned short*)(ws + 2691584);   // 294,912
    unsigned short* btabF  = (unsigned short*)(ws + 2986496);   // 1,376,256 bf16 frag table
    unsigned short* qkvb   = (unsigned short*)(ws + 4834304);   // [148960][576] bf16, 171.6MB
    unsigned short* h      = (unsigned short*)(ws + 4834304);   // [131072][768] bf16 (aliases, after proj)
    unsigned short* attn_c = (unsigned short*)(ws + 176436224); // [148960][192] bf16, 57.2MB
    float*          dout   = (float*)d_out;                     // fp32 out == x1 buffer

    mod_k<<<1, 256, 0, stream>>>(tvec, wa1, wa2, ba2, mod);
    prep_k<<<4416, 256, 0, stream>>>(w_qkv, w_proj, w1, w2, relb, wqkvT, wprojT, w1T, w2T, btabF);
    stats_f32_k<<<32768, 256, 0, stream>>>(x, stats1);

    gemm_k<4, 1, 0><<<dim3(5, 1164), 256, 0, stream>>>(
        nullptr, x, wqkvT, b_qkv, qkvb, nullptr, nullptr, stats1, mod, 0, 148960, 576, 192);
    attn_k<<<9120, 256, 0, stream>>>(qkvb, btabF, attn_c);
    gemm_k<2, 0, 2><<<dim3(3, 1164), 256, 0, stream>>>(
        attn_c, nullptr, wprojT, b_proj, nullptr, dout, x, nullptr, mod, 0, 148960, 192, 192);

    stats_f32_k<<<32768, 256, 0, stream>>>(dout, stats2);

    gemm_k<4, 2, 1><<<dim3(6, 1024), 256, 0, stream>>>(
        nullptr, dout, w1T, b1, h, nullptr, nullptr, stats2, mod, 0, 131072, 768, 192);
    gemm_k<2, 0, 3><<<dim3(3, 1024), 256, 0, stream>>>(
        h, nullptr, w2T, b2, nullptr, dout, nullptr, nullptr, mod, 0, 131072, 192, 768);
}

// Round 10
// 1016.422 us; speedup vs baseline: 1.4364x; 1.0039x over previous
//
#include <hip/hip_runtime.h>
#include <hip/hip_bf16.h>

// ---------- types ----------
typedef __bf16 bf16x8 __attribute__((ext_vector_type(8)));
typedef float  f32x4  __attribute__((ext_vector_type(4)));
typedef unsigned int u32x4 __attribute__((ext_vector_type(4)));

__device__ inline unsigned short f2bf(float f) {
    union { __hip_bfloat16 h; unsigned short u; } cv;
    cv.h = __float2bfloat16(f);
    return cv.u;
}
__device__ inline float bf2f(unsigned short u) {
    union { unsigned int i; float f; } c; c.i = ((unsigned int)u) << 16; return c.f;
}

// load 8 bf16 = two 8B halves at col +0 and col +16 (k-halves of 16x16x32)
__device__ inline bf16x8 load8(const unsigned short* p) {
    uint2 lo = *(const uint2*)(p);
    uint2 hi = *(const uint2*)(p + 16);
    u32x4 v; v[0] = lo.x; v[1] = lo.y; v[2] = hi.x; v[3] = hi.y;
    return __builtin_bit_cast(bf16x8, v);
}

__device__ inline f32x4 mfma16(bf16x8 a, bf16x8 b, f32x4 c) {
    return __builtin_amdgcn_mfma_f32_16x16x32_bf16(a, b, c, 0, 0, 0);
}

// window-row (global, 0..148959) -> spatial token (0..131071); false if pad
__device__ inline bool winmapT(int gg, int& T) {
    int win = gg / 98, n = gg % 98;
    int wdi = win / 190, rem = win % 190, whi = rem / 19, wwi = rem % 19;
    int td = n / 49, th = (n / 7) % 7, tw = n % 7;
    int sd = (wdi * 2 + td + 1) & 15;
    int sh = whi * 7 + th + 3; if (sh >= 70) sh -= 70;
    int sw = wwi * 7 + tw + 3; if (sw >= 133) sw -= 133;
    if (sh < 64 && sw < 128) { T = (sd * 64 + sh) * 128 + sw; return true; }
    return false;
}

// ---------- K0: mod = silu(t) @ wa1 @ wa2 + ba2  (1152 floats) ----------
__global__ __launch_bounds__(256) void mod_k(const float* __restrict__ t,
    const float* __restrict__ wa1, const float* __restrict__ wa2,
    const float* __restrict__ ba2, float* __restrict__ mod)
{
    __shared__ float st[192];
    __shared__ float a[24];
    int tid = threadIdx.x;
    if (tid < 192) { float x = t[tid]; st[tid] = x / (1.f + __expf(-x)); }
    __syncthreads();
    if (tid < 24) {
        float s = 0.f;
        for (int c = 0; c < 192; ++c) s += st[c] * wa1[c * 24 + tid];
        a[tid] = s;
    }
    __syncthreads();
    for (int j = tid; j < 1152; j += 256) {
        float s = ba2[j];
        for (int r = 0; r < 24; ++r) s += a[r] * wa2[r * 1152 + j];
        mod[j] = s;
    }
}

// ---------- K1: weight transposes + fragment-ordered bias table (swapped-QK layout) ----------
// btabF (bf16): [mt 8][h 6][fq 7][l16 16][lg 4][fkey 8][e 4]
//   value for (q = fq*16+l16, key = fkey*16+lg*4+e) = rel_bias(h,q,key) + mask(mt,q,key),
//   or -1e30 when fkey==7 | q>=98 | key>=98 (bakes pad masking; exp -> 0).
__global__ __launch_bounds__(256) void prep_k(
    const float* __restrict__ wqkv, const float* __restrict__ wproj,
    const float* __restrict__ w1, const float* __restrict__ w2,
    const float* __restrict__ relb,
    unsigned short* __restrict__ wqkvT, unsigned short* __restrict__ wprojT,
    unsigned short* __restrict__ w1T, unsigned short* __restrict__ w2T,
    unsigned short* __restrict__ btabF)
{
    int i = blockIdx.x * 256 + threadIdx.x;
    if (i < 110592) { int n = i / 192, k = i % 192; wqkvT[i] = f2bf(wqkv[k * 576 + n]); return; }
    i -= 110592;
    if (i < 36864)  { int n = i / 192, k = i % 192; wprojT[i] = f2bf(wproj[k * 192 + n]); return; }
    i -= 36864;
    if (i < 147456) { int n = i / 192, k = i % 192; w1T[i] = f2bf(w1[k * 768 + n]); return; }
    i -= 147456;
    if (i < 147456) { int n = i / 768, k = i % 768; w2T[i] = f2bf(w2[k * 192 + n]); return; }
    i -= 147456;
    if (i < 688128) {
        int mt = i / 86016, r1 = i % 86016;
        int h  = r1 / 14336, r2 = r1 % 14336;
        int fq = r2 / 2048,  r3 = r2 % 2048;
        int l16 = r3 / 128,  r4 = r3 % 128;
        int lg  = r4 / 32,   r5 = r4 % 32;
        int fkey = r5 / 4,   e  = r5 % 4;
        int q = fq * 16 + l16, key = fkey * 16 + lg * 4 + e;
        float val;
        if (fkey == 7 || q >= 98 || key >= 98) {
            val = -1e30f;
        } else {
            int tdn = q / 49, thn = (q / 7) % 7, twn = q % 7;
            int tdm = key / 49, thm = (key / 7) % 7, twm = key % 7;
            int idx = (tdn - tdm + 1) * 169 + (thn - thm + 6) * 13 + (twn - twm + 6);
            float b = relb[idx * 6 + h];
            int bd = mt & 1, bh = (mt >> 1) & 1, bw = (mt >> 2) & 1;
            int idn = (bd ? (tdn == 0 ? 1 : 2) : 0) * 9 + (bh ? (thn < 4 ? 1 : 2) : 0) * 3 + (bw ? (twn < 4 ? 1 : 2) : 0);
            int idm = (bd ? (tdm == 0 ? 1 : 2) : 0) * 9 + (bh ? (thm < 4 ? 1 : 2) : 0) * 3 + (bw ? (twm < 4 ? 1 : 2) : 0);
            val = b + ((idn != idm) ? -100.f : 0.f);
        }
        btabF[i] = f2bf(val);
    }
}

// ---------- stats: per-token LN mean/rstd over fp32 [tok][192] ----------
__global__ __launch_bounds__(256) void stats_f32_k(const float* __restrict__ x,
    float* __restrict__ st)
{
    int tok = blockIdx.x * 4 + (threadIdx.x >> 6);
    int lane = threadIdx.x & 63;
    const float* p = x + (size_t)tok * 192;
    float a = p[lane], b = p[64 + lane], c = p[128 + lane];
    float s = a + b + c, q = a * a + b * b + c * c;
    for (int m = 32; m; m >>= 1) { s += __shfl_xor(s, m); q += __shfl_xor(q, m); }
    if (lane == 0) {
        float mean = s * (1.f / 192.f);
        float var  = q * (1.f / 192.f) - mean * mean;
        st[2 * tok] = mean;
        st[2 * tok + 1] = rsqrtf(var + 1e-6f);
    }
}

// ---------- GEMM: C[M][N] = A[M][K](bf16) * BT[N][K]^T(bf16) + epilogue ----------
template<int FN, int STAGE, int EPI>
__global__ __launch_bounds__(256) void gemm_k(
    const unsigned short* __restrict__ A, const float* __restrict__ Af,
    const unsigned short* __restrict__ BT, const float* __restrict__ bias,
    unsigned short* __restrict__ outB, float* outF,
    const float* __restrict__ auxF, const float* __restrict__ stats,
    const float* __restrict__ mod, int row0, int M, int N, int K)
{
    constexpr int BN = FN * 32;
    __shared__ unsigned short As[128][44];
    __shared__ unsigned short Bs[BN][44];
    const int t = threadIdx.x;
    const int n0 = blockIdx.x * BN, m0 = blockIdx.y * 128;
    const int lr = t >> 2, lk = (t & 3) * 8;
    const int wid = t >> 6, lane = t & 63;
    const int lg = lane >> 4, l16 = lane & 15;
    const int wm = (wid >> 1) * 64, wn = (wid & 1) * (FN * 16);
    f32x4 acc[4][FN] = {};

    float mn[2] = {0.f, 0.f}, rs[2] = {0.f, 0.f};
    size_t sbase[2] = {0, 0};
    bool va[2] = {false, false};
    #pragma unroll
    for (int rr = 0; rr < 2; ++rr) {
        int g = m0 + lr + rr * 64;
        if (STAGE == 1) {
            int T;
            if (g < M && winmapT(row0 + g, T)) {
                va[rr] = true; sbase[rr] = (size_t)T * 192;
                mn[rr] = stats[2 * T]; rs[rr] = stats[2 * T + 1];
            }
        } else if (STAGE == 2) {
            int tok = row0 + g;
            sbase[rr] = (size_t)tok * 192;
            mn[rr] = stats[2 * tok]; rs[rr] = stats[2 * tok + 1];
        }
    }

    for (int kk = 0; kk < K; kk += 32) {
        #pragma unroll
        for (int rr = 0; rr < 2; ++rr) {
            int r = lr + rr * 64;
            int g = m0 + r;
            uint4 w = make_uint4(0u, 0u, 0u, 0u);
            if (STAGE == 0) {
                if (g < M) w = *(const uint4*)(A + (size_t)g * K + kk + lk);
            } else if (STAGE == 1) {
                if (va[rr]) {
                    float4 xa = *(const float4*)(Af + sbase[rr] + kk + lk);
                    float4 xb = *(const float4*)(Af + sbase[rr] + kk + lk + 4);
                    float xs[8] = {xa.x, xa.y, xa.z, xa.w, xb.x, xb.y, xb.z, xb.w};
                    unsigned short o[8];
                    #pragma unroll
                    for (int j = 0; j < 8; ++j) {
                        int c = kk + lk + j;
                        o[j] = f2bf((xs[j] - mn[rr]) * rs[rr] * (1.f + mod[192 + c]) + mod[c]);
                    }
                    w = make_uint4((unsigned)o[0] | ((unsigned)o[1] << 16), (unsigned)o[2] | ((unsigned)o[3] << 16),
                                   (unsigned)o[4] | ((unsigned)o[5] << 16), (unsigned)o[6] | ((unsigned)o[7] << 16));
                }
            } else { // STAGE 2
                float4 xa = *(const float4*)(Af + sbase[rr] + kk + lk);
                float4 xb = *(const float4*)(Af + sbase[rr] + kk + lk + 4);
                float xs[8] = {xa.x, xa.y, xa.z, xa.w, xb.x, xb.y, xb.z, xb.w};
                unsigned short o[8];
                #pragma unroll
                for (int j = 0; j < 8; ++j) {
                    int c = kk + lk + j;
                    o[j] = f2bf((xs[j] - mn[rr]) * rs[rr] * (1.f + mod[768 + c]) + mod[576 + c]);
                }
                w = make_uint4((unsigned)o[0] | ((unsigned)o[1] << 16), (unsigned)o[2] | ((unsigned)o[3] << 16),
                               (unsigned)o[4] | ((unsigned)o[5] << 16), (unsigned)o[6] | ((unsigned)o[7] << 16));
            }
            *(uint2*)(&As[r][lk])     = make_uint2(w.x, w.y);
            *(uint2*)(&As[r][lk + 4]) = make_uint2(w.z, w.w);
        }
        #pragma unroll
        for (int rr = 0; rr < BN / 64; ++rr) {
            int r = lr + rr * 64;
            int gn = n0 + r;
            uint4 w = make_uint4(0u, 0u, 0u, 0u);
            if (gn < N) w = *(const uint4*)(BT + (size_t)gn * K + kk + lk);
            *(uint2*)(&Bs[r][lk])     = make_uint2(w.x, w.y);
            *(uint2*)(&Bs[r][lk + 4]) = make_uint2(w.z, w.w);
        }
        __syncthreads();
        bf16x8 af[4], bv[FN];
        #pragma unroll
        for (int i = 0; i < 4; ++i) af[i] = load8(&As[wm + i * 16 + l16][4 * lg]);
        #pragma unroll
        for (int j = 0; j < FN; ++j) bv[j] = load8(&Bs[wn + j * 16 + l16][4 * lg]);
        #pragma unroll
        for (int i = 0; i < 4; ++i)
        #pragma unroll
        for (int j = 0; j < FN; ++j)
            acc[i][j] = mfma16(af[i], bv[j], acc[i][j]);
        __syncthreads();
    }

    #pragma unroll
    for (int i = 0; i < 4; ++i)
    #pragma unroll
    for (int j = 0; j < FN; ++j) {
        int gcol = n0 + wn + j * 16 + l16;
        if (gcol >= N) continue;
        float b = bias[gcol];
        #pragma unroll
        for (int e = 0; e < 4; ++e) {
            int grow = m0 + wm + i * 16 + lg * 4 + e;
            if (grow >= M) continue;
            float v = acc[i][j][e] + b;
            if (EPI == 0) {
                outB[(size_t)grow * N + gcol] = f2bf(v);
            } else if (EPI == 1) {
                float gl = 0.5f * v * (1.f + erff(v * 0.70710678118654752f));
                outB[(size_t)grow * N + gcol] = f2bf(gl);
            } else if (EPI == 2) {
                int T;
                if (winmapT(row0 + grow, T)) {
                    size_t idx = (size_t)T * 192 + gcol;
                    outF[idx] = auxF[idx] + mod[384 + gcol] * v;
                }
            } else {
                size_t idx = (size_t)(row0 + grow) * 192 + gcol;
                outF[idx] = outF[idx] + mod[960 + gcol] * v;
            }
        }
    }
}

// ---------- attention: swapped-operand QK^T, in-register P, ONE barrier ----------
// acc = mfma(K,Q): lane (l16,lg) holds S[q=fq*16+l16][key=fkey*16+lg*4+e] -> softmax
// in-lane + 2 shfl; P packs directly into PV A-fragments (no LDS round-trip).
// NOTE: only 7 key fragments exist (keys 0..111); PV chunk ks=3's upper half
// (keys 112..127) is zero-padded in the pack (round-9 bug: read acc[7] OOB).
__global__ __launch_bounds__(256) void attn_k(
    const unsigned short* __restrict__ qkv, const unsigned short* __restrict__ btabF,
    unsigned short* __restrict__ out)
{
    __shared__ __align__(16) unsigned short Qs[112 * 46];
    __shared__ __align__(16) unsigned short Ks[112 * 46];
    __shared__ __align__(16) unsigned short VT[32 * 142];

    const int blk = blockIdx.x;
    const int win = blk / 6, h = blk % 6;
    const int t = threadIdx.x;
    const int wid = t >> 6, lg = (t >> 4) & 3, l16 = t & 15;
    const size_t rb = (size_t)win * 98;

    const int wdi = win / 190, remw = win % 190, whi = remw / 19, wwi = remw % 19;
    const int mt = (wdi == 7 ? 1 : 0) | (whi == 9 ? 2 : 0) | (wwi == 18 ? 4 : 0);
    const unsigned short* btF = btabF + (size_t)(mt * 6 + h) * 14336;

    // ---- stage Q,K rows; V transposed; zero Q/K pad rows and V pad cols ----
    for (int i = t; i < 98 * 4; i += 256) {
        int r = i >> 2, cg = (i & 3) * 8;
        uint4 q = *(const uint4*)(qkv + (rb + r) * 576 + h * 32 + cg);
        uint4 k = *(const uint4*)(qkv + (rb + r) * 576 + 192 + h * 32 + cg);
        *(uint2*)(Qs + r * 46 + cg)     = make_uint2(q.x, q.y);
        *(uint2*)(Qs + r * 46 + cg + 4) = make_uint2(q.z, q.w);
        *(uint2*)(Ks + r * 46 + cg)     = make_uint2(k.x, k.y);
        *(uint2*)(Ks + r * 46 + cg + 4) = make_uint2(k.z, k.w);
    }
    for (int i = t; i < 14 * 32; i += 256) {      // Q/K pad rows 98..111 -> 0
        int r = 98 + (i >> 5), c = i & 31;
        Qs[r * 46 + c] = 0; Ks[r * 46 + c] = 0;
    }
    if (t < 392) {                                 // V^T direct: m = t>>2, dims (t&3)*8..+7
        uint4 v = *(const uint4*)(qkv + (rb + (t >> 2)) * 576 + 384 + h * 32 + (t & 3) * 8);
        const unsigned short* vp = (const unsigned short*)&v;
        int m = t >> 2, c0 = (t & 3) * 8;
        #pragma unroll
        for (int j = 0; j < 8; ++j) VT[(c0 + j) * 142 + m] = vp[j];
    }
    {
        int t2 = t + 256;
        if (t2 < 392) {
            uint4 v = *(const uint4*)(qkv + (rb + (t2 >> 2)) * 576 + 384 + h * 32 + (t2 & 3) * 8);
            const unsigned short* vp = (const unsigned short*)&v;
            int m = t2 >> 2, c0 = (t2 & 3) * 8;
            #pragma unroll
            for (int j = 0; j < 8; ++j) VT[(c0 + j) * 142 + m] = vp[j];
        }
    }
    for (int i = t; i < 32 * 30; i += 256) { int c = i / 30, m = 98 + i % 30; VT[c * 142 + m] = 0; }
    __syncthreads();   // the ONLY barrier

    const float SCALE = 0.17677669529663687f;
    #pragma unroll
    for (int fi = 0; fi < 2; ++fi) {
        const int fq = wid + fi * 4;
        if (fq >= 7) break;   // wave-uniform; only wid==3,fi==1

        // bias fragment: 32 bf16 contiguous (64 B) per thread
        const uint4* bp = (const uint4*)(btF + fq * 2048 + l16 * 128 + lg * 32);
        uint4 b0 = bp[0], b1 = bp[1], b2 = bp[2], b3 = bp[3];
        const unsigned bt32[16] = {b0.x, b0.y, b0.z, b0.w, b1.x, b1.y, b1.z, b1.w,
                                   b2.x, b2.y, b2.z, b2.w, b3.x, b3.y, b3.z, b3.w};

        bf16x8 qa = load8(Qs + (fq * 16 + l16) * 46 + 4 * lg);
        f32x4 acc[7];
        #pragma unroll
        for (int fk = 0; fk < 7; ++fk) {
            bf16x8 kb = load8(Ks + (fk * 16 + l16) * 46 + 4 * lg);
            f32x4 z = {};
            acc[fk] = mfma16(kb, qa, z);   // swapped: lane-local S rows
        }

        // softmax: 28 in-lane + cross-lg reduce (2 shfl)
        float mx = -1e30f;
        #pragma unroll
        for (int fk = 0; fk < 7; ++fk)
        #pragma unroll
        for (int e = 0; e < 4; ++e) {
            unsigned short bu = (unsigned short)(bt32[fk * 2 + (e >> 1)] >> ((e & 1) * 16));
            float s = fmaf(acc[fk][e], SCALE, bf2f(bu));
            acc[fk][e] = s;
            mx = fmaxf(mx, s);
        }
        mx = fmaxf(mx, __shfl_xor(mx, 16));
        mx = fmaxf(mx, __shfl_xor(mx, 32));
        float sum = 0.f;
        #pragma unroll
        for (int fk = 0; fk < 7; ++fk)
        #pragma unroll
        for (int e = 0; e < 4; ++e) {
            float p = __expf(acc[fk][e] - mx);
            acc[fk][e] = p;
            sum += p;
        }
        sum += __shfl_xor(sum, 16);
        sum += __shfl_xor(sum, 32);
        float rinv = 1.f / sum;

        // pack P rows into PV A-fragments (pure register); keys 112..127 -> 0
        bf16x8 sa[4];
        #pragma unroll
        for (int ks = 0; ks < 4; ++ks) {
            u32x4 w;
            w[0] = (unsigned)f2bf(acc[2 * ks][0]) | ((unsigned)f2bf(acc[2 * ks][1]) << 16);
            w[1] = (unsigned)f2bf(acc[2 * ks][2]) | ((unsigned)f2bf(acc[2 * ks][3]) << 16);
            if (ks < 3) {
                w[2] = (unsigned)f2bf(acc[2 * ks + 1][0]) | ((unsigned)f2bf(acc[2 * ks + 1][1]) << 16);
                w[3] = (unsigned)f2bf(acc[2 * ks + 1][2]) | ((unsigned)f2bf(acc[2 * ks + 1][3]) << 16);
            } else {
                w[2] = 0u; w[3] = 0u;
            }
            sa[ks] = __builtin_bit_cast(bf16x8, w);
        }
        // redistribute 1/rowsum from lane l16=q to lanes with lg*4+e=q
        float rv[4];
        #pragma unroll
        for (int e = 0; e < 4; ++e) rv[e] = __shfl(rinv, lg * 4 + e);

        // PV: O rows = this wave's queries
        #pragma unroll
        for (int fn = 0; fn < 2; ++fn) {
            f32x4 o = {};
            #pragma unroll
            for (int ks = 0; ks < 4; ++ks) {
                bf16x8 vb = load8(VT + (fn * 16 + l16) * 142 + ks * 32 + 4 * lg);
                o = mfma16(sa[ks], vb, o);
            }
            #pragma unroll
            for (int e = 0; e < 4; ++e) {
                int r = fq * 16 + lg * 4 + e;
                if (r < 98) {
                    out[(rb + r) * 192 + h * 32 + fn * 16 + l16] = f2bf(o[e] * rv[e]);
                }
            }
        }
    }
}

// ---------- launch ----------
// ws_size = 384 MiB. Un-chunked pipeline, 9 launches. d_out (fp32) is ALSO the x1 buffer.
extern "C" void kernel_launch(void* const* d_in, const int* in_sizes, int n_in,
                              void* d_out, int out_size, void* d_ws, size_t ws_size,
                              hipStream_t stream)
{
    const float* x      = (const float*)d_in[0];
    const float* tvec   = (const float*)d_in[2];
    const float* w_qkv  = (const float*)d_in[3];
    const float* b_qkv  = (const float*)d_in[4];
    const float* relb   = (const float*)d_in[5];
    const float* w_proj = (const float*)d_in[6];
    const float* b_proj = (const float*)d_in[7];
    const float* w1     = (const float*)d_in[8];
    const float* b1     = (const float*)d_in[9];
    const float* w2     = (const float*)d_in[10];
    const float* b2     = (const float*)d_in[11];
    const float* wa1    = (const float*)d_in[12];
    const float* wa2    = (const float*)d_in[13];
    const float* ba2    = (const float*)d_in[14];

    char* ws = (char*)d_ws;
    float*          mod    = (float*)ws;                        // 4,608
    float*          stats1 = (float*)(ws + 4608);               // 1,048,576
    float*          stats2 = (float*)(ws + 1053184);            // 1,048,576
    unsigned short* wqkvT  = (unsigned short*)(ws + 2101760);   // 221,184
    unsigned short* wprojT = (unsigned short*)(ws + 2322944);   // 73,728
    unsigned short* w1T    = (unsigned short*)(ws + 2396672);   // 294,912
    unsigned short* w2T    = (unsigned short*)(ws + 2691584);   // 294,912
    unsigned short* btabF  = (unsigned short*)(ws + 2986496);   // 1,376,256 bf16 frag table
    unsigned short* qkvb   = (unsigned short*)(ws + 4834304);   // [148960][576] bf16, 171.6MB
    unsigned short* h      = (unsigned short*)(ws + 4834304);   // [131072][768] bf16 (aliases, after proj)
    unsigned short* attn_c = (unsigned short*)(ws + 176436224); // [148960][192] bf16, 57.2MB
    float*          dout   = (float*)d_out;                     // fp32 out == x1 buffer

    mod_k<<<1, 256, 0, stream>>>(tvec, wa1, wa2, ba2, mod);
    prep_k<<<4416, 256, 0, stream>>>(w_qkv, w_proj, w1, w2, relb, wqkvT, wprojT, w1T, w2T, btabF);
    stats_f32_k<<<32768, 256, 0, stream>>>(x, stats1);

    gemm_k<4, 1, 0><<<dim3(5, 1164), 256, 0, stream>>>(
        nullptr, x, wqkvT, b_qkv, qkvb, nullptr, nullptr, stats1, mod, 0, 148960, 576, 192);
    attn_k<<<9120, 256, 0, stream>>>(qkvb, btabF, attn_c);
    gemm_k<2, 0, 2><<<dim3(3, 1164), 256, 0, stream>>>(
        attn_c, nullptr, wprojT, b_proj, nullptr, dout, x, nullptr, mod, 0, 148960, 192, 192);

    stats_f32_k<<<32768, 256, 0, stream>>>(dout, stats2);

    gemm_k<4, 2, 1><<<dim3(6, 1024), 256, 0, stream>>>(
        nullptr, dout, w1T, b1, h, nullptr, nullptr, stats2, mod, 0, 131072, 768, 192);
    gemm_k<2, 0, 3><<<dim3(3, 1024), 256, 0, stream>>>(
        h, nullptr, w2T, b2, nullptr, dout, nullptr, nullptr, mod, 0, 131072, 192, 768);
}

// Round 11
// 1009.720 us; speedup vs baseline: 1.4459x; 1.0066x over previous
//
#include <hip/hip_runtime.h>
#include <hip/hip_bf16.h>

// ---------- types ----------
typedef __bf16 bf16x8 __attribute__((ext_vector_type(8)));
typedef float  f32x4  __attribute__((ext_vector_type(4)));
typedef unsigned int u32x4 __attribute__((ext_vector_type(4)));

__device__ inline unsigned short f2bf(float f) {
    union { __hip_bfloat16 h; unsigned short u; } cv;
    cv.h = __float2bfloat16(f);
    return cv.u;
}
__device__ inline float bf2f(unsigned short u) {
    union { unsigned int i; float f; } c; c.i = ((unsigned int)u) << 16; return c.f;
}

// load 8 bf16 = two 8B halves at col +0 and col +16 (k-halves of 16x16x32)
__device__ inline bf16x8 load8(const unsigned short* p) {
    uint2 lo = *(const uint2*)(p);
    uint2 hi = *(const uint2*)(p + 16);
    u32x4 v; v[0] = lo.x; v[1] = lo.y; v[2] = hi.x; v[3] = hi.y;
    return __builtin_bit_cast(bf16x8, v);
}

__device__ inline f32x4 mfma16(bf16x8 a, bf16x8 b, f32x4 c) {
    return __builtin_amdgcn_mfma_f32_16x16x32_bf16(a, b, c, 0, 0, 0);
}

// window-row (global, 0..148959) -> spatial token (0..131071); false if pad
__device__ inline bool winmapT(int gg, int& T) {
    int win = gg / 98, n = gg % 98;
    int wdi = win / 190, rem = win % 190, whi = rem / 19, wwi = rem % 19;
    int td = n / 49, th = (n / 7) % 7, tw = n % 7;
    int sd = (wdi * 2 + td + 1) & 15;
    int sh = whi * 7 + th + 3; if (sh >= 70) sh -= 70;
    int sw = wwi * 7 + tw + 3; if (sw >= 133) sw -= 133;
    if (sh < 64 && sw < 128) { T = (sd * 64 + sh) * 128 + sw; return true; }
    return false;
}

// ---------- K0: mod = silu(t) @ wa1 @ wa2 + ba2  (1152 floats) ----------
__global__ __launch_bounds__(256) void mod_k(const float* __restrict__ t,
    const float* __restrict__ wa1, const float* __restrict__ wa2,
    const float* __restrict__ ba2, float* __restrict__ mod)
{
    __shared__ float st[192];
    __shared__ float a[24];
    int tid = threadIdx.x;
    if (tid < 192) { float x = t[tid]; st[tid] = x / (1.f + __expf(-x)); }
    __syncthreads();
    if (tid < 24) {
        float s = 0.f;
        for (int c = 0; c < 192; ++c) s += st[c] * wa1[c * 24 + tid];
        a[tid] = s;
    }
    __syncthreads();
    for (int j = tid; j < 1152; j += 256) {
        float s = ba2[j];
        for (int r = 0; r < 24; ++r) s += a[r] * wa2[r * 1152 + j];
        mod[j] = s;
    }
}

// ---------- K1: weight transposes + fragment-ordered bias table (swapped-QK layout) ----------
// btabF (bf16): [mt 8][h 6][fq 7][l16 16][lg 4][fkey 8][e 4]
__global__ __launch_bounds__(256) void prep_k(
    const float* __restrict__ wqkv, const float* __restrict__ wproj,
    const float* __restrict__ w1, const float* __restrict__ w2,
    const float* __restrict__ relb,
    unsigned short* __restrict__ wqkvT, unsigned short* __restrict__ wprojT,
    unsigned short* __restrict__ w1T, unsigned short* __restrict__ w2T,
    unsigned short* __restrict__ btabF)
{
    int i = blockIdx.x * 256 + threadIdx.x;
    if (i < 110592) { int n = i / 192, k = i % 192; wqkvT[i] = f2bf(wqkv[k * 576 + n]); return; }
    i -= 110592;
    if (i < 36864)  { int n = i / 192, k = i % 192; wprojT[i] = f2bf(wproj[k * 192 + n]); return; }
    i -= 36864;
    if (i < 147456) { int n = i / 192, k = i % 192; w1T[i] = f2bf(w1[k * 768 + n]); return; }
    i -= 147456;
    if (i < 147456) { int n = i / 768, k = i % 768; w2T[i] = f2bf(w2[k * 192 + n]); return; }
    i -= 147456;
    if (i < 688128) {
        int mt = i / 86016, r1 = i % 86016;
        int h  = r1 / 14336, r2 = r1 % 14336;
        int fq = r2 / 2048,  r3 = r2 % 2048;
        int l16 = r3 / 128,  r4 = r3 % 128;
        int lg  = r4 / 32,   r5 = r4 % 32;
        int fkey = r5 / 4,   e  = r5 % 4;
        int q = fq * 16 + l16, key = fkey * 16 + lg * 4 + e;
        float val;
        if (fkey == 7 || q >= 98 || key >= 98) {
            val = -1e30f;
        } else {
            int tdn = q / 49, thn = (q / 7) % 7, twn = q % 7;
            int tdm = key / 49, thm = (key / 7) % 7, twm = key % 7;
            int idx = (tdn - tdm + 1) * 169 + (thn - thm + 6) * 13 + (twn - twm + 6);
            float b = relb[idx * 6 + h];
            int bd = mt & 1, bh = (mt >> 1) & 1, bw = (mt >> 2) & 1;
            int idn = (bd ? (tdn == 0 ? 1 : 2) : 0) * 9 + (bh ? (thn < 4 ? 1 : 2) : 0) * 3 + (bw ? (twn < 4 ? 1 : 2) : 0);
            int idm = (bd ? (tdm == 0 ? 1 : 2) : 0) * 9 + (bh ? (thm < 4 ? 1 : 2) : 0) * 3 + (bw ? (twm < 4 ? 1 : 2) : 0);
            val = b + ((idn != idm) ? -100.f : 0.f);
        }
        btabF[i] = f2bf(val);
    }
}

// ---------- stats: per-token LN mean/rstd over fp32 [tok][192] ----------
__global__ __launch_bounds__(256) void stats_f32_k(const float* __restrict__ x,
    float* __restrict__ st)
{
    int tok = blockIdx.x * 4 + (threadIdx.x >> 6);
    int lane = threadIdx.x & 63;
    const float* p = x + (size_t)tok * 192;
    float a = p[lane], b = p[64 + lane], c = p[128 + lane];
    float s = a + b + c, q = a * a + b * b + c * c;
    for (int m = 32; m; m >>= 1) { s += __shfl_xor(s, m); q += __shfl_xor(q, m); }
    if (lane == 0) {
        float mean = s * (1.f / 192.f);
        float var  = q * (1.f / 192.f) - mean * mean;
        st[2 * tok] = mean;
        st[2 * tok + 1] = rsqrtf(var + 1e-6f);
    }
}

// ---------- GEMM: C[M][N] = A[M][K](bf16) * BT[N][K]^T(bf16) + epilogue ----------
// EPI: 0 = bias -> head-major qkv chunks [h*3+which][row][32]; 1 = bias+gelu->bf16;
//      2 = proj scatter residual->fp32 out; 3 = fc2 in-place final residual on fp32 out
template<int FN, int STAGE, int EPI>
__global__ __launch_bounds__(256) void gemm_k(
    const unsigned short* __restrict__ A, const float* __restrict__ Af,
    const unsigned short* __restrict__ BT, const float* __restrict__ bias,
    unsigned short* __restrict__ outB, float* outF,
    const float* __restrict__ auxF, const float* __restrict__ stats,
    const float* __restrict__ mod, int row0, int M, int N, int K)
{
    constexpr int BN = FN * 32;
    __shared__ unsigned short As[128][44];
    __shared__ unsigned short Bs[BN][44];
    const int t = threadIdx.x;
    const int n0 = blockIdx.x * BN, m0 = blockIdx.y * 128;
    const int lr = t >> 2, lk = (t & 3) * 8;
    const int wid = t >> 6, lane = t & 63;
    const int lg = lane >> 4, l16 = lane & 15;
    const int wm = (wid >> 1) * 64, wn = (wid & 1) * (FN * 16);
    f32x4 acc[4][FN] = {};

    float mn[2] = {0.f, 0.f}, rs[2] = {0.f, 0.f};
    size_t sbase[2] = {0, 0};
    bool va[2] = {false, false};
    #pragma unroll
    for (int rr = 0; rr < 2; ++rr) {
        int g = m0 + lr + rr * 64;
        if (STAGE == 1) {
            int T;
            if (g < M && winmapT(row0 + g, T)) {
                va[rr] = true; sbase[rr] = (size_t)T * 192;
                mn[rr] = stats[2 * T]; rs[rr] = stats[2 * T + 1];
            }
        } else if (STAGE == 2) {
            int tok = row0 + g;
            sbase[rr] = (size_t)tok * 192;
            mn[rr] = stats[2 * tok]; rs[rr] = stats[2 * tok + 1];
        }
    }

    for (int kk = 0; kk < K; kk += 32) {
        #pragma unroll
        for (int rr = 0; rr < 2; ++rr) {
            int r = lr + rr * 64;
            int g = m0 + r;
            uint4 w = make_uint4(0u, 0u, 0u, 0u);
            if (STAGE == 0) {
                if (g < M) w = *(const uint4*)(A + (size_t)g * K + kk + lk);
            } else if (STAGE == 1) {
                if (va[rr]) {
                    float4 xa = *(const float4*)(Af + sbase[rr] + kk + lk);
                    float4 xb = *(const float4*)(Af + sbase[rr] + kk + lk + 4);
                    float xs[8] = {xa.x, xa.y, xa.z, xa.w, xb.x, xb.y, xb.z, xb.w};
                    unsigned short o[8];
                    #pragma unroll
                    for (int j = 0; j < 8; ++j) {
                        int c = kk + lk + j;
                        o[j] = f2bf((xs[j] - mn[rr]) * rs[rr] * (1.f + mod[192 + c]) + mod[c]);
                    }
                    w = make_uint4((unsigned)o[0] | ((unsigned)o[1] << 16), (unsigned)o[2] | ((unsigned)o[3] << 16),
                                   (unsigned)o[4] | ((unsigned)o[5] << 16), (unsigned)o[6] | ((unsigned)o[7] << 16));
                }
            } else { // STAGE 2
                float4 xa = *(const float4*)(Af + sbase[rr] + kk + lk);
                float4 xb = *(const float4*)(Af + sbase[rr] + kk + lk + 4);
                float xs[8] = {xa.x, xa.y, xa.z, xa.w, xb.x, xb.y, xb.z, xb.w};
                unsigned short o[8];
                #pragma unroll
                for (int j = 0; j < 8; ++j) {
                    int c = kk + lk + j;
                    o[j] = f2bf((xs[j] - mn[rr]) * rs[rr] * (1.f + mod[768 + c]) + mod[576 + c]);
                }
                w = make_uint4((unsigned)o[0] | ((unsigned)o[1] << 16), (unsigned)o[2] | ((unsigned)o[3] << 16),
                               (unsigned)o[4] | ((unsigned)o[5] << 16), (unsigned)o[6] | ((unsigned)o[7] << 16));
            }
            *(uint2*)(&As[r][lk])     = make_uint2(w.x, w.y);
            *(uint2*)(&As[r][lk + 4]) = make_uint2(w.z, w.w);
        }
        #pragma unroll
        for (int rr = 0; rr < BN / 64; ++rr) {
            int r = lr + rr * 64;
            int gn = n0 + r;
            uint4 w = make_uint4(0u, 0u, 0u, 0u);
            if (gn < N) w = *(const uint4*)(BT + (size_t)gn * K + kk + lk);
            *(uint2*)(&Bs[r][lk])     = make_uint2(w.x, w.y);
            *(uint2*)(&Bs[r][lk + 4]) = make_uint2(w.z, w.w);
        }
        __syncthreads();
        bf16x8 af[4], bv[FN];
        #pragma unroll
        for (int i = 0; i < 4; ++i) af[i] = load8(&As[wm + i * 16 + l16][4 * lg]);
        #pragma unroll
        for (int j = 0; j < FN; ++j) bv[j] = load8(&Bs[wn + j * 16 + l16][4 * lg]);
        #pragma unroll
        for (int i = 0; i < 4; ++i)
        #pragma unroll
        for (int j = 0; j < FN; ++j)
            acc[i][j] = mfma16(af[i], bv[j], acc[i][j]);
        __syncthreads();
    }

    #pragma unroll
    for (int i = 0; i < 4; ++i)
    #pragma unroll
    for (int j = 0; j < FN; ++j) {
        int gcol = n0 + wn + j * 16 + l16;
        if (gcol >= N) continue;
        float b = bias[gcol];
        #pragma unroll
        for (int e = 0; e < 4; ++e) {
            int grow = m0 + wm + i * 16 + lg * 4 + e;
            if (grow >= M) continue;
            float v = acc[i][j][e] + b;
            if (EPI == 0) {
                // head-major qkv: gcol = which*192 + h*32 + c
                int which = gcol / 192, hh = (gcol / 32) % 6, c = gcol & 31;
                outB[((size_t)(hh * 3 + which) * 148960 + grow) * 32 + c] = f2bf(v);
            } else if (EPI == 1) {
                float gl = 0.5f * v * (1.f + erff(v * 0.70710678118654752f));
                outB[(size_t)grow * N + gcol] = f2bf(gl);
            } else if (EPI == 2) {
                int T;
                if (winmapT(row0 + grow, T)) {
                    size_t idx = (size_t)T * 192 + gcol;
                    outF[idx] = auxF[idx] + mod[384 + gcol] * v;
                }
            } else {
                size_t idx = (size_t)(row0 + grow) * 192 + gcol;
                outF[idx] = outF[idx] + mod[960 + gcol] * v;
            }
        }
    }
}

// ---------- attention: head-major contiguous reads, Q direct-to-reg, one barrier ----------
// qkv2 layout [ci=h*3+{0:Q,1:K,2:V}][row][32]: per (win,h) block the Q/K/V panels are
// three contiguous 6.3KB streams. Q has no cross-wave reuse -> global->reg load8,
// no Qs LDS. K staged to LDS (shared by all waves), V transposed to VT.
__global__ __launch_bounds__(256) void attn_k(
    const unsigned short* __restrict__ qkv, const unsigned short* __restrict__ btabF,
    unsigned short* __restrict__ out)
{
    __shared__ __align__(16) unsigned short Ks[112 * 46];
    __shared__ __align__(16) unsigned short VT[32 * 142];

    const int blk = blockIdx.x;
    const int win = blk / 6, h = blk % 6;
    const int t = threadIdx.x;
    const int wid = t >> 6, lg = (t >> 4) & 3, l16 = t & 15;
    const size_t rb = (size_t)win * 98;

    const unsigned short* Qg = qkv + (size_t)(h * 3 + 0) * 148960 * 32;
    const unsigned short* Kg = qkv + (size_t)(h * 3 + 1) * 148960 * 32;
    const unsigned short* Vg = qkv + (size_t)(h * 3 + 2) * 148960 * 32;

    const int wdi = win / 190, remw = win % 190, whi = remw / 19, wwi = remw % 19;
    const int mt = (wdi == 7 ? 1 : 0) | (whi == 9 ? 2 : 0) | (wwi == 18 ? 4 : 0);
    const unsigned short* btF = btabF + (size_t)(mt * 6 + h) * 14336;

    // ---- stage K (contiguous); V -> VT transpose; zero K pad rows, V pad cols ----
    for (int i = t; i < 392; i += 256) {
        int r = i >> 2, cg = (i & 3) * 8;
        uint4 k = *(const uint4*)(Kg + (rb + r) * 32 + cg);
        *(uint2*)(Ks + r * 46 + cg)     = make_uint2(k.x, k.y);
        *(uint2*)(Ks + r * 46 + cg + 4) = make_uint2(k.z, k.w);
    }
    for (int i = t; i < 14 * 32; i += 256) {
        int r = 98 + (i >> 5), c = i & 31;
        Ks[r * 46 + c] = 0;
    }
    if (t < 392) {
        uint4 v = *(const uint4*)(Vg + (rb + (t >> 2)) * 32 + (t & 3) * 8);
        const unsigned short* vp = (const unsigned short*)&v;
        int m = t >> 2, c0 = (t & 3) * 8;
        #pragma unroll
        for (int j = 0; j < 8; ++j) VT[(c0 + j) * 142 + m] = vp[j];
    }
    {
        int t2 = t + 256;
        if (t2 < 392) {
            uint4 v = *(const uint4*)(Vg + (rb + (t2 >> 2)) * 32 + (t2 & 3) * 8);
            const unsigned short* vp = (const unsigned short*)&v;
            int m = t2 >> 2, c0 = (t2 & 3) * 8;
            #pragma unroll
            for (int j = 0; j < 8; ++j) VT[(c0 + j) * 142 + m] = vp[j];
        }
    }
    for (int i = t; i < 32 * 30; i += 256) { int c = i / 30, m = 98 + i % 30; VT[c * 142 + m] = 0; }
    __syncthreads();   // the ONLY barrier

    __builtin_amdgcn_s_setprio(1);
    const float SCALE = 0.17677669529663687f;
    #pragma unroll
    for (int fi = 0; fi < 2; ++fi) {
        const int fq = wid + fi * 4;
        if (fq >= 7) break;   // wave-uniform

        // bias fragment: 32 bf16 contiguous (64 B) per thread
        const uint4* bp = (const uint4*)(btF + fq * 2048 + l16 * 128 + lg * 32);
        uint4 b0 = bp[0], b1 = bp[1], b2 = bp[2], b3 = bp[3];
        const unsigned bt32[16] = {b0.x, b0.y, b0.z, b0.w, b1.x, b1.y, b1.z, b1.w,
                                   b2.x, b2.y, b2.z, b2.w, b3.x, b3.y, b3.z, b3.w};

        // Q fragment direct from global (row used by exactly one wave)
        bf16x8 qa = load8(Qg + (rb + fq * 16 + l16) * 32 + 4 * lg);
        f32x4 acc[7];
        #pragma unroll
        for (int fk = 0; fk < 7; ++fk) {
            bf16x8 kb = load8(Ks + (fk * 16 + l16) * 46 + 4 * lg);
            f32x4 z = {};
            acc[fk] = mfma16(kb, qa, z);   // swapped: lane-local S rows
        }

        // softmax: 28 in-lane + cross-lg reduce (2 shfl)
        float mx = -1e30f;
        #pragma unroll
        for (int fk = 0; fk < 7; ++fk)
        #pragma unroll
        for (int e = 0; e < 4; ++e) {
            unsigned short bu = (unsigned short)(bt32[fk * 2 + (e >> 1)] >> ((e & 1) * 16));
            float s = fmaf(acc[fk][e], SCALE, bf2f(bu));
            acc[fk][e] = s;
            mx = fmaxf(mx, s);
        }
        mx = fmaxf(mx, __shfl_xor(mx, 16));
        mx = fmaxf(mx, __shfl_xor(mx, 32));
        float sum = 0.f;
        #pragma unroll
        for (int fk = 0; fk < 7; ++fk)
        #pragma unroll
        for (int e = 0; e < 4; ++e) {
            float p = __expf(acc[fk][e] - mx);
            acc[fk][e] = p;
            sum += p;
        }
        sum += __shfl_xor(sum, 16);
        sum += __shfl_xor(sum, 32);
        float rinv = 1.f / sum;

        // pack P rows into PV A-fragments (pure register); keys 112..127 -> 0
        bf16x8 sa[4];
        #pragma unroll
        for (int ks = 0; ks < 4; ++ks) {
            u32x4 w;
            w[0] = (unsigned)f2bf(acc[2 * ks][0]) | ((unsigned)f2bf(acc[2 * ks][1]) << 16);
            w[1] = (unsigned)f2bf(acc[2 * ks][2]) | ((unsigned)f2bf(acc[2 * ks][3]) << 16);
            if (ks < 3) {
                w[2] = (unsigned)f2bf(acc[2 * ks + 1][0]) | ((unsigned)f2bf(acc[2 * ks + 1][1]) << 16);
                w[3] = (unsigned)f2bf(acc[2 * ks + 1][2]) | ((unsigned)f2bf(acc[2 * ks + 1][3]) << 16);
            } else {
                w[2] = 0u; w[3] = 0u;
            }
            sa[ks] = __builtin_bit_cast(bf16x8, w);
        }
        // redistribute 1/rowsum from lane l16=q to lanes with lg*4+e=q
        float rv[4];
        #pragma unroll
        for (int e = 0; e < 4; ++e) rv[e] = __shfl(rinv, lg * 4 + e);

        // PV: O rows = this wave's queries
        #pragma unroll
        for (int fn = 0; fn < 2; ++fn) {
            f32x4 o = {};
            #pragma unroll
            for (int ks = 0; ks < 4; ++ks) {
                bf16x8 vb = load8(VT + (fn * 16 + l16) * 142 + ks * 32 + 4 * lg);
                o = mfma16(sa[ks], vb, o);
            }
            #pragma unroll
            for (int e = 0; e < 4; ++e) {
                int r = fq * 16 + lg * 4 + e;
                if (r < 98) {
                    out[(rb + r) * 192 + h * 32 + fn * 16 + l16] = f2bf(o[e] * rv[e]);
                }
            }
        }
    }
    __builtin_amdgcn_s_setprio(0);
}

// ---------- launch ----------
// ws_size = 384 MiB. Un-chunked pipeline, 9 launches. d_out (fp32) is ALSO the x1 buffer.
extern "C" void kernel_launch(void* const* d_in, const int* in_sizes, int n_in,
                              void* d_out, int out_size, void* d_ws, size_t ws_size,
                              hipStream_t stream)
{
    const float* x      = (const float*)d_in[0];
    const float* tvec   = (const float*)d_in[2];
    const float* w_qkv  = (const float*)d_in[3];
    const float* b_qkv  = (const float*)d_in[4];
    const float* relb   = (const float*)d_in[5];
    const float* w_proj = (const float*)d_in[6];
    const float* b_proj = (const float*)d_in[7];
    const float* w1     = (const float*)d_in[8];
    const float* b1     = (const float*)d_in[9];
    const float* w2     = (const float*)d_in[10];
    const float* b2     = (const float*)d_in[11];
    const float* wa1    = (const float*)d_in[12];
    const float* wa2    = (const float*)d_in[13];
    const float* ba2    = (const float*)d_in[14];

    char* ws = (char*)d_ws;
    float*          mod    = (float*)ws;                        // 4,608
    float*          stats1 = (float*)(ws + 4608);               // 1,048,576
    float*          stats2 = (float*)(ws + 1053184);            // 1,048,576
    unsigned short* wqkvT  = (unsigned short*)(ws + 2101760);   // 221,184
    unsigned short* wprojT = (unsigned short*)(ws + 2322944);   // 73,728
    unsigned short* w1T    = (unsigned short*)(ws + 2396672);   // 294,912
    unsigned short* w2T    = (unsigned short*)(ws + 2691584);   // 294,912
    unsigned short* btabF  = (unsigned short*)(ws + 2986496);   // 1,376,256 bf16 frag table
    unsigned short* qkvb   = (unsigned short*)(ws + 4834304);   // [18 ci][148960][32] bf16, 171.6MB
    unsigned short* h      = (unsigned short*)(ws + 4834304);   // [131072][768] bf16 (aliases, after proj)
    unsigned short* attn_c = (unsigned short*)(ws + 176436224); // [148960][192] bf16, 57.2MB
    float*          dout   = (float*)d_out;                     // fp32 out == x1 buffer

    mod_k<<<1, 256, 0, stream>>>(tvec, wa1, wa2, ba2, mod);
    prep_k<<<4416, 256, 0, stream>>>(w_qkv, w_proj, w1, w2, relb, wqkvT, wprojT, w1T, w2T, btabF);
    stats_f32_k<<<32768, 256, 0, stream>>>(x, stats1);

    gemm_k<4, 1, 0><<<dim3(5, 1164), 256, 0, stream>>>(
        nullptr, x, wqkvT, b_qkv, qkvb, nullptr, nullptr, stats1, mod, 0, 148960, 576, 192);
    attn_k<<<9120, 256, 0, stream>>>(qkvb, btabF, attn_c);
    gemm_k<2, 0, 2><<<dim3(3, 1164), 256, 0, stream>>>(
        attn_c, nullptr, wprojT, b_proj, nullptr, dout, x, nullptr, mod, 0, 148960, 192, 192);

    stats_f32_k<<<32768, 256, 0, stream>>>(dout, stats2);

    gemm_k<4, 2, 1><<<dim3(6, 1024), 256, 0, stream>>>(
        nullptr, dout, w1T, b1, h, nullptr, nullptr, stats2, mod, 0, 131072, 768, 192);
    gemm_k<2, 0, 3><<<dim3(3, 1024), 256, 0, stream>>>(
        h, nullptr, w2T, b2, nullptr, dout, nullptr, nullptr, mod, 0, 131072, 192, 768);
}

// Round 12
// 950.628 us; speedup vs baseline: 1.5358x; 1.0622x over previous
//
#include <hip/hip_runtime.h>
#include <hip/hip_bf16.h>

// ---------- types ----------
typedef __bf16 bf16x8 __attribute__((ext_vector_type(8)));
typedef float  f32x4  __attribute__((ext_vector_type(4)));
typedef unsigned int u32x4 __attribute__((ext_vector_type(4)));

__device__ inline unsigned short f2bf(float f) {
    union { __hip_bfloat16 h; unsigned short u; } cv;
    cv.h = __float2bfloat16(f);
    return cv.u;
}
__device__ inline float bf2f(unsigned short u) {
    union { unsigned int i; float f; } c; c.i = ((unsigned int)u) << 16; return c.f;
}

// load 8 bf16 = two 8B halves at col +0 and col +16 (k-halves of 16x16x32)
__device__ inline bf16x8 load8(const unsigned short* p) {
    uint2 lo = *(const uint2*)(p);
    uint2 hi = *(const uint2*)(p + 16);
    u32x4 v; v[0] = lo.x; v[1] = lo.y; v[2] = hi.x; v[3] = hi.y;
    return __builtin_bit_cast(bf16x8, v);
}

__device__ inline f32x4 mfma16(bf16x8 a, bf16x8 b, f32x4 c) {
    return __builtin_amdgcn_mfma_f32_16x16x32_bf16(a, b, c, 0, 0, 0);
}

// window-row (global, 0..148959) -> spatial token (0..131071); false if pad
__device__ inline bool winmapT(int gg, int& T) {
    int win = gg / 98, n = gg % 98;
    int wdi = win / 190, rem = win % 190, whi = rem / 19, wwi = rem % 19;
    int td = n / 49, th = (n / 7) % 7, tw = n % 7;
    int sd = (wdi * 2 + td + 1) & 15;
    int sh = whi * 7 + th + 3; if (sh >= 70) sh -= 70;
    int sw = wwi * 7 + tw + 3; if (sw >= 133) sw -= 133;
    if (sh < 64 && sw < 128) { T = (sd * 64 + sh) * 128 + sw; return true; }
    return false;
}

// bijective XCD swizzle (m204): consecutive result-ids land on the same XCD
__device__ inline int xcd_swz(int orig, int nwg) {
    int q = nwg >> 3, r = nwg & 7;
    int xcd = orig & 7, idx = orig >> 3;
    return (xcd < r ? xcd * (q + 1) : r * (q + 1) + (xcd - r) * q) + idx;
}

// ---------- K0: mod = silu(t) @ wa1 @ wa2 + ba2  (1152 floats) ----------
__global__ __launch_bounds__(256) void mod_k(const float* __restrict__ t,
    const float* __restrict__ wa1, const float* __restrict__ wa2,
    const float* __restrict__ ba2, float* __restrict__ mod)
{
    __shared__ float st[192];
    __shared__ float a[24];
    int tid = threadIdx.x;
    if (tid < 192) { float x = t[tid]; st[tid] = x / (1.f + __expf(-x)); }
    __syncthreads();
    if (tid < 24) {
        float s = 0.f;
        for (int c = 0; c < 192; ++c) s += st[c] * wa1[c * 24 + tid];
        a[tid] = s;
    }
    __syncthreads();
    for (int j = tid; j < 1152; j += 256) {
        float s = ba2[j];
        for (int r = 0; r < 24; ++r) s += a[r] * wa2[r * 1152 + j];
        mod[j] = s;
    }
}

// ---------- K1: weight transposes + fragment-ordered bias table (swapped-QK layout) ----------
// btabF (bf16): [mt 8][h 6][fq 7][l16 16][lg 4][fkey 8][e 4]
__global__ __launch_bounds__(256) void prep_k(
    const float* __restrict__ wqkv, const float* __restrict__ wproj,
    const float* __restrict__ w1, const float* __restrict__ w2,
    const float* __restrict__ relb,
    unsigned short* __restrict__ wqkvT, unsigned short* __restrict__ wprojT,
    unsigned short* __restrict__ w1T, unsigned short* __restrict__ w2T,
    unsigned short* __restrict__ btabF)
{
    int i = blockIdx.x * 256 + threadIdx.x;
    if (i < 110592) { int n = i / 192, k = i % 192; wqkvT[i] = f2bf(wqkv[k * 576 + n]); return; }
    i -= 110592;
    if (i < 36864)  { int n = i / 192, k = i % 192; wprojT[i] = f2bf(wproj[k * 192 + n]); return; }
    i -= 36864;
    if (i < 147456) { int n = i / 192, k = i % 192; w1T[i] = f2bf(w1[k * 768 + n]); return; }
    i -= 147456;
    if (i < 147456) { int n = i / 768, k = i % 768; w2T[i] = f2bf(w2[k * 192 + n]); return; }
    i -= 147456;
    if (i < 688128) {
        int mt = i / 86016, r1 = i % 86016;
        int h  = r1 / 14336, r2 = r1 % 14336;
        int fq = r2 / 2048,  r3 = r2 % 2048;
        int l16 = r3 / 128,  r4 = r3 % 128;
        int lg  = r4 / 32,   r5 = r4 % 32;
        int fkey = r5 / 4,   e  = r5 % 4;
        int q = fq * 16 + l16, key = fkey * 16 + lg * 4 + e;
        float val;
        if (fkey == 7 || q >= 98 || key >= 98) {
            val = -1e30f;
        } else {
            int tdn = q / 49, thn = (q / 7) % 7, twn = q % 7;
            int tdm = key / 49, thm = (key / 7) % 7, twm = key % 7;
            int idx = (tdn - tdm + 1) * 169 + (thn - thm + 6) * 13 + (twn - twm + 6);
            float b = relb[idx * 6 + h];
            int bd = mt & 1, bh = (mt >> 1) & 1, bw = (mt >> 2) & 1;
            int idn = (bd ? (tdn == 0 ? 1 : 2) : 0) * 9 + (bh ? (thn < 4 ? 1 : 2) : 0) * 3 + (bw ? (twn < 4 ? 1 : 2) : 0);
            int idm = (bd ? (tdm == 0 ? 1 : 2) : 0) * 9 + (bh ? (thm < 4 ? 1 : 2) : 0) * 3 + (bw ? (twm < 4 ? 1 : 2) : 0);
            val = b + ((idn != idm) ? -100.f : 0.f);
        }
        btabF[i] = f2bf(val);
    }
}

// ---------- lnwin: x -> LN+modulate(MSA) + window gather -> ywin bf16 [148960][192] ----------
__global__ __launch_bounds__(256) void lnwin_k(const float* __restrict__ x,
    const float* __restrict__ mod, unsigned short* __restrict__ ywin)
{
    int tok = blockIdx.x * 4 + (threadIdx.x >> 6);
    int lane = threadIdx.x & 63;
    int T;
    size_t ob = (size_t)tok * 192;
    if (winmapT(tok, T)) {
        const float* p = x + (size_t)T * 192;
        float x0 = p[lane], xa = p[64 + lane], xb = p[128 + lane];
        float s = x0 + xa + xb, q = x0 * x0 + xa * xa + xb * xb;
        for (int m = 32; m; m >>= 1) { s += __shfl_xor(s, m); q += __shfl_xor(q, m); }
        float mean = s * (1.f / 192.f);
        float var  = q * (1.f / 192.f) - mean * mean;
        float rstd = rsqrtf(var + 1e-6f);
        ywin[ob + lane]       = f2bf((x0 - mean) * rstd * (1.f + mod[192 + lane])       + mod[lane]);
        ywin[ob + 64 + lane]  = f2bf((xa - mean) * rstd * (1.f + mod[192 + 64 + lane])  + mod[64 + lane]);
        ywin[ob + 128 + lane] = f2bf((xb - mean) * rstd * (1.f + mod[192 + 128 + lane]) + mod[128 + lane]);
    } else {
        ywin[ob + lane] = 0; ywin[ob + 64 + lane] = 0; ywin[ob + 128 + lane] = 0;
    }
}

// ---------- ln2: x1(fp32, straight) -> LN+modulate(MLP) -> y2 bf16 [131072][192] ----------
__global__ __launch_bounds__(256) void ln2_k(const float* __restrict__ x1,
    const float* __restrict__ mod, unsigned short* __restrict__ y2)
{
    int tok = blockIdx.x * 4 + (threadIdx.x >> 6);
    int lane = threadIdx.x & 63;
    const float* p = x1 + (size_t)tok * 192;
    float x0 = p[lane], xa = p[64 + lane], xb = p[128 + lane];
    float s = x0 + xa + xb, q = x0 * x0 + xa * xa + xb * xb;
    for (int m = 32; m; m >>= 1) { s += __shfl_xor(s, m); q += __shfl_xor(q, m); }
    float mean = s * (1.f / 192.f);
    float var  = q * (1.f / 192.f) - mean * mean;
    float rstd = rsqrtf(var + 1e-6f);
    size_t ob = (size_t)tok * 192;
    y2[ob + lane]       = f2bf((x0 - mean) * rstd * (1.f + mod[768 + lane])       + mod[576 + lane]);
    y2[ob + 64 + lane]  = f2bf((xa - mean) * rstd * (1.f + mod[768 + 64 + lane])  + mod[576 + 64 + lane]);
    y2[ob + 128 + lane] = f2bf((xb - mean) * rstd * (1.f + mod[768 + 128 + lane]) + mod[576 + 128 + lane]);
}

// ---------- GEMM: C[M][N] = A[M][K](bf16) * BT[N][K]^T + epilogue. Plain-A (STAGE0 only). ----------
// 1-D grid, XCD-swizzled: wg%nx = n-block, wg/nx = m-block. LDS stride 40 shorts (b128 staging).
// EPI: 0 = bias -> head-major qkv [h*3+which][row][32]; 1 = bias+gelu -> bf16;
//      2 = proj scatter residual -> fp32 outF; 3 = fc2 in-place final residual on fp32 outF
template<int FN, int EPI>
__global__ __launch_bounds__(256) void gemm_k(
    const unsigned short* __restrict__ A, const unsigned short* __restrict__ BT,
    const float* __restrict__ bias, unsigned short* __restrict__ outB, float* outF,
    const float* __restrict__ auxF, const float* __restrict__ mod,
    int M, int N, int K, int nx)
{
    constexpr int BN = FN * 32;
    __shared__ unsigned short As[128][40];
    __shared__ unsigned short Bs[BN][40];
    const int t = threadIdx.x;
    const int wg = xcd_swz(blockIdx.x, gridDim.x);
    const int n0 = (wg % nx) * BN, m0 = (wg / nx) * 128;
    const int lr = t >> 2, lk = (t & 3) * 8;
    const int wid = t >> 6, lane = t & 63;
    const int lg = lane >> 4, l16 = lane & 15;
    const int wm = (wid >> 1) * 64, wn = (wid & 1) * (FN * 16);
    f32x4 acc[4][FN] = {};

    for (int kk = 0; kk < K; kk += 32) {
        #pragma unroll
        for (int rr = 0; rr < 2; ++rr) {
            int r = lr + rr * 64;
            int g = m0 + r;
            uint4 w = make_uint4(0u, 0u, 0u, 0u);
            if (g < M) w = *(const uint4*)(A + (size_t)g * K + kk + lk);
            *(uint4*)(&As[r][lk]) = w;
        }
        #pragma unroll
        for (int rr = 0; rr < BN / 64; ++rr) {
            int r = lr + rr * 64;
            int gn = n0 + r;
            uint4 w = make_uint4(0u, 0u, 0u, 0u);
            if (gn < N) w = *(const uint4*)(BT + (size_t)gn * K + kk + lk);
            *(uint4*)(&Bs[r][lk]) = w;
        }
        __syncthreads();
        bf16x8 af[4], bv[FN];
        #pragma unroll
        for (int i = 0; i < 4; ++i) af[i] = load8(&As[wm + i * 16 + l16][4 * lg]);
        #pragma unroll
        for (int j = 0; j < FN; ++j) bv[j] = load8(&Bs[wn + j * 16 + l16][4 * lg]);
        #pragma unroll
        for (int i = 0; i < 4; ++i)
        #pragma unroll
        for (int j = 0; j < FN; ++j)
            acc[i][j] = mfma16(af[i], bv[j], acc[i][j]);
        __syncthreads();
    }

    #pragma unroll
    for (int i = 0; i < 4; ++i)
    #pragma unroll
    for (int j = 0; j < FN; ++j) {
        int gcol = n0 + wn + j * 16 + l16;
        if (gcol >= N) continue;
        float b = bias[gcol];
        #pragma unroll
        for (int e = 0; e < 4; ++e) {
            int grow = m0 + wm + i * 16 + lg * 4 + e;
            if (grow >= M) continue;
            float v = acc[i][j][e] + b;
            if (EPI == 0) {
                int which = gcol / 192, hh = (gcol / 32) % 6, c = gcol & 31;
                outB[((size_t)(hh * 3 + which) * 148960 + grow) * 32 + c] = f2bf(v);
            } else if (EPI == 1) {
                float gl = 0.5f * v * (1.f + erff(v * 0.70710678118654752f));
                outB[(size_t)grow * N + gcol] = f2bf(gl);
            } else if (EPI == 2) {
                int T;
                if (winmapT(grow, T)) {
                    size_t idx = (size_t)T * 192 + gcol;
                    outF[idx] = auxF[idx] + mod[384 + gcol] * v;
                }
            } else {
                size_t idx = (size_t)grow * 192 + gcol;
                outF[idx] = outF[idx] + mod[960 + gcol] * v;
            }
        }
    }
}

// ---------- attention: head-major streams, Q+bias prefetched, one barrier ----------
__global__ __launch_bounds__(256) void attn_k(
    const unsigned short* __restrict__ qkv, const unsigned short* __restrict__ btabF,
    unsigned short* __restrict__ out)
{
    __shared__ __align__(16) unsigned short Ks[112 * 46];
    __shared__ __align__(16) unsigned short VT[32 * 142];

    // XCD swizzle (9120 = 8*1140): same-XCD blocks stream consecutive windows of one head
    const int wg = xcd_swz(blockIdx.x, 9120);
    const int h = wg / 1520, win = wg % 1520;
    const int t = threadIdx.x;
    const int wid = t >> 6, lg = (t >> 4) & 3, l16 = t & 15;
    const size_t rb = (size_t)win * 98;

    const unsigned short* Qg = qkv + (size_t)(h * 3 + 0) * 148960 * 32;
    const unsigned short* Kg = qkv + (size_t)(h * 3 + 1) * 148960 * 32;
    const unsigned short* Vg = qkv + (size_t)(h * 3 + 2) * 148960 * 32;

    const int wdi = win / 190, remw = win % 190, whi = remw / 19, wwi = remw % 19;
    const int mt = (wdi == 7 ? 1 : 0) | (whi == 9 ? 2 : 0) | (wwi == 18 ? 4 : 0);
    const unsigned short* btF = btabF + (size_t)(mt * 6 + h) * 14336;

    // ---- prefetch Q fragments + bias fragments (latency hides under staging) ----
    bf16x8 qa[2];
    uint4 btr[2][4];
    #pragma unroll
    for (int fi = 0; fi < 2; ++fi) {
        int fq = wid + fi * 4;
        int fqc = (fq < 7) ? fq : 0;
        qa[fi] = load8(Qg + (rb + fqc * 16 + l16) * 32 + 4 * lg);
        const uint4* bp = (const uint4*)(btF + fqc * 2048 + l16 * 128 + lg * 32);
        btr[fi][0] = bp[0]; btr[fi][1] = bp[1]; btr[fi][2] = bp[2]; btr[fi][3] = bp[3];
    }

    // ---- stage K (contiguous); V -> VT transpose; zero K pad rows, V pad cols ----
    for (int i = t; i < 392; i += 256) {
        int r = i >> 2, cg = (i & 3) * 8;
        uint4 k = *(const uint4*)(Kg + (rb + r) * 32 + cg);
        *(uint2*)(Ks + r * 46 + cg)     = make_uint2(k.x, k.y);
        *(uint2*)(Ks + r * 46 + cg + 4) = make_uint2(k.z, k.w);
    }
    for (int i = t; i < 14 * 32; i += 256) {
        int r = 98 + (i >> 5), c = i & 31;
        Ks[r * 46 + c] = 0;
    }
    if (t < 392) {
        uint4 v = *(const uint4*)(Vg + (rb + (t >> 2)) * 32 + (t & 3) * 8);
        const unsigned short* vp = (const unsigned short*)&v;
        int m = t >> 2, c0 = (t & 3) * 8;
        #pragma unroll
        for (int j = 0; j < 8; ++j) VT[(c0 + j) * 142 + m] = vp[j];
    }
    {
        int t2 = t + 256;
        if (t2 < 392) {
            uint4 v = *(const uint4*)(Vg + (rb + (t2 >> 2)) * 32 + (t2 & 3) * 8);
            const unsigned short* vp = (const unsigned short*)&v;
            int m = t2 >> 2, c0 = (t2 & 3) * 8;
            #pragma unroll
            for (int j = 0; j < 8; ++j) VT[(c0 + j) * 142 + m] = vp[j];
        }
    }
    for (int i = t; i < 32 * 30; i += 256) { int c = i / 30, m = 98 + i % 30; VT[c * 142 + m] = 0; }
    __syncthreads();   // the ONLY barrier

    __builtin_amdgcn_s_setprio(1);
    const float SCALE = 0.17677669529663687f;
    #pragma unroll
    for (int fi = 0; fi < 2; ++fi) {
        const int fq = wid + fi * 4;
        if (fq >= 7) break;   // wave-uniform

        const unsigned bt32[16] = {btr[fi][0].x, btr[fi][0].y, btr[fi][0].z, btr[fi][0].w,
                                   btr[fi][1].x, btr[fi][1].y, btr[fi][1].z, btr[fi][1].w,
                                   btr[fi][2].x, btr[fi][2].y, btr[fi][2].z, btr[fi][2].w,
                                   btr[fi][3].x, btr[fi][3].y, btr[fi][3].z, btr[fi][3].w};

        f32x4 acc[7];
        #pragma unroll
        for (int fk = 0; fk < 7; ++fk) {
            bf16x8 kb = load8(Ks + (fk * 16 + l16) * 46 + 4 * lg);
            f32x4 z = {};
            acc[fk] = mfma16(kb, qa[fi], z);   // swapped: lane-local S rows
        }

        float mx = -1e30f;
        #pragma unroll
        for (int fk = 0; fk < 7; ++fk)
        #pragma unroll
        for (int e = 0; e < 4; ++e) {
            unsigned short bu = (unsigned short)(bt32[fk * 2 + (e >> 1)] >> ((e & 1) * 16));
            float s = fmaf(acc[fk][e], SCALE, bf2f(bu));
            acc[fk][e] = s;
            mx = fmaxf(mx, s);
        }
        mx = fmaxf(mx, __shfl_xor(mx, 16));
        mx = fmaxf(mx, __shfl_xor(mx, 32));
        float sum = 0.f;
        #pragma unroll
        for (int fk = 0; fk < 7; ++fk)
        #pragma unroll
        for (int e = 0; e < 4; ++e) {
            float p = __expf(acc[fk][e] - mx);
            acc[fk][e] = p;
            sum += p;
        }
        sum += __shfl_xor(sum, 16);
        sum += __shfl_xor(sum, 32);
        float rinv = 1.f / sum;

        bf16x8 sa[4];
        #pragma unroll
        for (int ks = 0; ks < 4; ++ks) {
            u32x4 w;
            w[0] = (unsigned)f2bf(acc[2 * ks][0]) | ((unsigned)f2bf(acc[2 * ks][1]) << 16);
            w[1] = (unsigned)f2bf(acc[2 * ks][2]) | ((unsigned)f2bf(acc[2 * ks][3]) << 16);
            if (ks < 3) {
                w[2] = (unsigned)f2bf(acc[2 * ks + 1][0]) | ((unsigned)f2bf(acc[2 * ks + 1][1]) << 16);
                w[3] = (unsigned)f2bf(acc[2 * ks + 1][2]) | ((unsigned)f2bf(acc[2 * ks + 1][3]) << 16);
            } else {
                w[2] = 0u; w[3] = 0u;
            }
            sa[ks] = __builtin_bit_cast(bf16x8, w);
        }
        float rv[4];
        #pragma unroll
        for (int e = 0; e < 4; ++e) rv[e] = __shfl(rinv, lg * 4 + e);

        #pragma unroll
        for (int fn = 0; fn < 2; ++fn) {
            f32x4 o = {};
            #pragma unroll
            for (int ks = 0; ks < 4; ++ks) {
                bf16x8 vb = load8(VT + (fn * 16 + l16) * 142 + ks * 32 + 4 * lg);
                o = mfma16(sa[ks], vb, o);
            }
            #pragma unroll
            for (int e = 0; e < 4; ++e) {
                int r = fq * 16 + lg * 4 + e;
                if (r < 98) {
                    out[(rb + r) * 192 + h * 32 + fn * 16 + l16] = f2bf(o[e] * rv[e]);
                }
            }
        }
    }
    __builtin_amdgcn_s_setprio(0);
}

// ---------- launch ----------
// ws_size = 384 MiB. d_out (fp32 [131072][192]) is ALSO the x1 buffer.
// layout: tables < 4.4MB; qkvb @4.83M (171.6MB); attn_c @176.4M (57.2MB);
//         h @4.83M (201.3MB, aliases qkvb+attn_c head, both dead at fc1);
//         ywin @233.6M (57.2MB); y2b @290.8M (50.3MB). span ~341MB < 384MB.
extern "C" void kernel_launch(void* const* d_in, const int* in_sizes, int n_in,
                              void* d_out, int out_size, void* d_ws, size_t ws_size,
                              hipStream_t stream)
{
    const float* x      = (const float*)d_in[0];
    const float* tvec   = (const float*)d_in[2];
    const float* w_qkv  = (const float*)d_in[3];
    const float* b_qkv  = (const float*)d_in[4];
    const float* relb   = (const float*)d_in[5];
    const float* w_proj = (const float*)d_in[6];
    const float* b_proj = (const float*)d_in[7];
    const float* w1     = (const float*)d_in[8];
    const float* b1     = (const float*)d_in[9];
    const float* w2     = (const float*)d_in[10];
    const float* b2     = (const float*)d_in[11];
    const float* wa1    = (const float*)d_in[12];
    const float* wa2    = (const float*)d_in[13];
    const float* ba2    = (const float*)d_in[14];

    char* ws = (char*)d_ws;
    float*          mod    = (float*)ws;                        // 4,608
    unsigned short* wqkvT  = (unsigned short*)(ws + 2101760);   // 221,184
    unsigned short* wprojT = (unsigned short*)(ws + 2322944);   // 73,728
    unsigned short* w1T    = (unsigned short*)(ws + 2396672);   // 294,912
    unsigned short* w2T    = (unsigned short*)(ws + 2691584);   // 294,912
    unsigned short* btabF  = (unsigned short*)(ws + 2986496);   // 1,376,256
    unsigned short* qkvb   = (unsigned short*)(ws + 4834304);   // [18][148960][32] bf16
    unsigned short* h      = (unsigned short*)(ws + 4834304);   // [131072][768] bf16 (aliases)
    unsigned short* attn_c = (unsigned short*)(ws + 176436224); // [148960][192] bf16
    unsigned short* ywin   = (unsigned short*)(ws + 233636864); // [148960][192] bf16
    unsigned short* y2b    = (unsigned short*)(ws + 290837504); // [131072][192] bf16
    float*          dout   = (float*)d_out;                     // fp32 out == x1 buffer

    mod_k<<<1, 256, 0, stream>>>(tvec, wa1, wa2, ba2, mod);
    prep_k<<<4416, 256, 0, stream>>>(w_qkv, w_proj, w1, w2, relb, wqkvT, wprojT, w1T, w2T, btabF);
    lnwin_k<<<37240, 256, 0, stream>>>(x, mod, ywin);

    // qkv: [148960][192] @ [576][192]^T -> head-major qkvb
    gemm_k<4, 0><<<5 * 1164, 256, 0, stream>>>(
        ywin, wqkvT, b_qkv, qkvb, nullptr, nullptr, mod, 148960, 576, 192, 5);
    attn_k<<<9120, 256, 0, stream>>>(qkvb, btabF, attn_c);
    // proj + residual scatter -> fp32 x1 (in d_out)
    gemm_k<2, 2><<<3 * 1164, 256, 0, stream>>>(
        attn_c, wprojT, b_proj, nullptr, dout, x, mod, 148960, 192, 192, 3);

    ln2_k<<<32768, 256, 0, stream>>>(dout, mod, y2b);

    gemm_k<4, 1><<<6 * 1024, 256, 0, stream>>>(
        y2b, w1T, b1, h, nullptr, nullptr, mod, 131072, 768, 192, 6);
    gemm_k<2, 3><<<3 * 1024, 256, 0, stream>>>(
        h, w2T, b2, nullptr, dout, nullptr, mod, 131072, 192, 768, 3);
}